// Round 3
// baseline (603.024 us; speedup 1.0000x reference)
//
#include <hip/hip_runtime.h>

#define DEV __device__ __forceinline__

typedef __bf16 bf16x8 __attribute__((ext_vector_type(8)));
typedef float f32x4 __attribute__((ext_vector_type(4)));

DEV float b2f(__bf16 v) { return (float)v; }
DEV __bf16 f2b(float v) { return (__bf16)v; }

// ---------------------------------------------------------------- dtype detect (3-way)
__global__ void detect_k(const unsigned short* __restrict__ q, int* __restrict__ mode) {
  const int lane = threadIdx.x & 63;
  int cntNaN = 0, cntSmall = 0;
  for (int i = lane; i < 16384; i += 64) {
    const unsigned ef = (q[i] >> 7) & 0xFF;
    if (ef == 0xFF) cntNaN++;
    if (ef < 0x70) cntSmall++;
  }
#pragma unroll
  for (int o = 32; o > 0; o >>= 1) {
    cntNaN += __shfl_down(cntNaN, o);
    cntSmall += __shfl_down(cntSmall, o);
  }
  if (lane == 0) *mode = (cntNaN >= 4) ? 1 : ((cntSmall > 2000) ? 2 : 0);
}

// ---------------------------------------------------------------- fused small-vector convert
struct CvtJobs {
  const void* src[9];
  __bf16* dst[9];
};
__global__ __launch_bounds__(256) void cvt_all_k(CvtJobs J, const int* __restrict__ mode) {
  const int bb = blockIdx.x;
  int job, off;
  if (bb < 4) { job = bb; off = 0; }
  else if (bb == 4) { job = 4; off = 0; }
  else if (bb < 9) { job = 5; off = (bb - 5) * 1024; }
  else { job = 6 + (bb - 9); off = 0; }
  const int n = (job == 4) ? 64 : (job == 5) ? 4096 : 1024;
  const int m = *mode;
  const void* s = J.src[job];
  __bf16* d = J.dst[job];
  const int rem = n - off;
  const int cnt = rem > 1024 ? 1024 : rem;
  for (int i = threadIdx.x; i < cnt; i += 256) {
    const int idx = off + i;
    const float v = (m == 1) ? ((const float*)s)[idx]
                  : (m == 2) ? (float)((const _Float16*)s)[idx]
                             : b2f(((const __bf16*)s)[idx]);
    d[idx] = f2b(v);
  }
}

// ---------------------------------------------------------------- fused LDS-tiled transpose+convert
struct TJobs {
  const void* src[5];
  __bf16* dst[5];
};
__global__ __launch_bounds__(256) void tcvt_all_k(TJobs J, const int* __restrict__ mode) {
  __shared__ __bf16 tile[64][68];
  const void* in = J.src[blockIdx.z];
  __bf16* out = J.dst[blockIdx.z];
  const int c0 = blockIdx.x * 64, r0 = blockIdx.y * 64;
  const int tid = threadIdx.x;
  const int m = *mode;
  for (int i = tid; i < 64 * 16; i += 256) {
    int r = i >> 4, cc = (i & 15) * 4;
    const size_t base = (size_t)(r0 + r) * 1024 + c0 + cc;
    if (m == 1) {
      float4 v = *(const float4*)((const float*)in + base);
      tile[r][cc + 0] = f2b(v.x);
      tile[r][cc + 1] = f2b(v.y);
      tile[r][cc + 2] = f2b(v.z);
      tile[r][cc + 3] = f2b(v.w);
    } else if (m == 2) {
      const _Float16* p = (const _Float16*)in + base;
      tile[r][cc + 0] = f2b((float)p[0]);
      tile[r][cc + 1] = f2b((float)p[1]);
      tile[r][cc + 2] = f2b((float)p[2]);
      tile[r][cc + 3] = f2b((float)p[3]);
    } else {
      *(uint2*)&tile[r][cc] = *(const uint2*)((const __bf16*)in + base);
    }
  }
  __syncthreads();
  for (int i = tid; i < 64 * 16; i += 256) {
    int c = i >> 4, rr = (i & 15) * 4;
    union { __bf16 h[4]; uint2 u; } pk;
    pk.h[0] = tile[rr + 0][c];
    pk.h[1] = tile[rr + 1][c];
    pk.h[2] = tile[rr + 2][c];
    pk.h[3] = tile[rr + 3][c];
    *(uint2*)&out[(size_t)(c0 + c) * 1024 + r0 + rr] = pk.u;
  }
}

// ---------------------------------------------------------------- GEMM BM=64 x BN=128 (2x occupancy vs 128x128 at these grids)
// C[M][N] = A[M][K] @ BT[N][K]^T + bias[N]. grid (N/128, M/64). Waves 2x2 over (64,128).
template <bool OUT_F32, bool A_CHK>
__global__ __launch_bounds__(256) void gemm64m_k(const void* __restrict__ Av,
                                                 const __bf16* __restrict__ BT,
                                                 const __bf16* __restrict__ bias,
                                                 void* __restrict__ Cout,
                                                 int M, int N, int K,
                                                 const int* __restrict__ mode) {
  __shared__ __bf16 As[64][72];
  __shared__ __bf16 Bs[128][72];
  const int tid = threadIdx.x, lane = tid & 63, wv = tid >> 6;
  const int quad = lane >> 4, l16 = lane & 15;
  const int m0 = blockIdx.y * 64, n0 = blockIdx.x * 128;
  const int wm = (wv >> 1) * 32, wn = (wv & 1) * 64;
  int am = 0;
  if constexpr (A_CHK) am = *mode;
  f32x4 acc[2][4] = {};
  for (int k0 = 0; k0 < K; k0 += 64) {
    if (A_CHK && am == 1) {
      for (int i = tid; i < 512; i += 256) {
        int r = i >> 3, kc = (i & 7) * 8;
        const float* ap = (const float*)Av + (size_t)(m0 + r) * K + k0 + kc;
        float4 v0 = *(const float4*)ap, v1 = *(const float4*)(ap + 4);
        union { __bf16 h[8]; int4 u; } pk;
        pk.h[0] = f2b(v0.x); pk.h[1] = f2b(v0.y); pk.h[2] = f2b(v0.z); pk.h[3] = f2b(v0.w);
        pk.h[4] = f2b(v1.x); pk.h[5] = f2b(v1.y); pk.h[6] = f2b(v1.z); pk.h[7] = f2b(v1.w);
        *(int4*)&As[r][kc] = pk.u;
      }
    } else if (A_CHK && am == 2) {
      for (int i = tid; i < 512; i += 256) {
        int r = i >> 3, kc = (i & 7) * 8;
        const _Float16* ap = (const _Float16*)Av + (size_t)(m0 + r) * K + k0 + kc;
        union { __bf16 h[8]; int4 u; } pk;
#pragma unroll
        for (int t = 0; t < 8; t++) pk.h[t] = f2b((float)ap[t]);
        *(int4*)&As[r][kc] = pk.u;
      }
    } else {
      for (int i = tid; i < 512; i += 256) {
        int r = i >> 3, kc = (i & 7) * 8;
        *(int4*)&As[r][kc] = *(const int4*)((const __bf16*)Av + (size_t)(m0 + r) * K + k0 + kc);
      }
    }
    for (int i = tid; i < 1024; i += 256) {
      int r = i >> 3, kc = (i & 7) * 8;
      *(int4*)&Bs[r][kc] = *(const int4*)&BT[(size_t)(n0 + r) * K + k0 + kc];
    }
    __syncthreads();
#pragma unroll
    for (int ks = 0; ks < 64; ks += 32) {
      const int ka = ks + quad * 8;
      bf16x8 af[2], bfr[4];
#pragma unroll
      for (int i = 0; i < 2; i++) af[i] = *(const bf16x8*)&As[wm + i * 16 + l16][ka];
#pragma unroll
      for (int j = 0; j < 4; j++) bfr[j] = *(const bf16x8*)&Bs[wn + j * 16 + l16][ka];
#pragma unroll
      for (int i = 0; i < 2; i++)
#pragma unroll
        for (int j = 0; j < 4; j++)
          acc[i][j] = __builtin_amdgcn_mfma_f32_16x16x32_bf16(af[i], bfr[j], acc[i][j], 0, 0, 0);
    }
    __syncthreads();
  }
#pragma unroll
  for (int j = 0; j < 4; j++) {
    const int col = n0 + wn + j * 16 + l16;
    const float bv = b2f(bias[col]);
#pragma unroll
    for (int i = 0; i < 2; i++) {
#pragma unroll
      for (int r = 0; r < 4; r++) {
        const int row = m0 + wm + i * 16 + quad * 4 + r;
        const float v = acc[i][j][r] + bv;
        if (OUT_F32)
          ((float*)Cout)[(size_t)row * N + col] = v;
        else
          ((__bf16*)Cout)[(size_t)row * N + col] = f2b(v);
      }
    }
  }
}

// ---------------------------------------------------------------- fused Q/R/H GEMM, BM=64 x BN=128
// BT3 = [3072][1024] (WqT|WrT|WhT), bias3[3072]. grid (24, M/64).
__global__ __launch_bounds__(256) void qrh64_k(const __bf16* __restrict__ A,
                                               const __bf16* __restrict__ BT3,
                                               const __bf16* __restrict__ bias3,
                                               __bf16* __restrict__ Qf,
                                               __bf16* __restrict__ Rf,
                                               __bf16* __restrict__ Hv,
                                               int M) {
  __shared__ __bf16 As[64][72];
  __shared__ __bf16 Bs[128][72];
  const int tid = threadIdx.x, lane = tid & 63, wv = tid >> 6;
  const int quad = lane >> 4, l16 = lane & 15;
  const int m0 = blockIdx.y * 64, n0g = blockIdx.x * 128;
  const int which = n0g >> 10, n0 = n0g & 1023;
  __bf16* out = (which == 0) ? Qf : (which == 1) ? Rf : Hv;
  const int wm = (wv >> 1) * 32, wn = (wv & 1) * 64;
  f32x4 acc[2][4] = {};
  for (int k0 = 0; k0 < 1024; k0 += 64) {
    for (int i = tid; i < 512; i += 256) {
      int r = i >> 3, kc = (i & 7) * 8;
      *(int4*)&As[r][kc] = *(const int4*)&A[(size_t)(m0 + r) * 1024 + k0 + kc];
    }
    for (int i = tid; i < 1024; i += 256) {
      int r = i >> 3, kc = (i & 7) * 8;
      *(int4*)&Bs[r][kc] = *(const int4*)&BT3[(size_t)(n0g + r) * 1024 + k0 + kc];
    }
    __syncthreads();
#pragma unroll
    for (int ks = 0; ks < 64; ks += 32) {
      const int ka = ks + quad * 8;
      bf16x8 af[2], bfr[4];
#pragma unroll
      for (int i = 0; i < 2; i++) af[i] = *(const bf16x8*)&As[wm + i * 16 + l16][ka];
#pragma unroll
      for (int j = 0; j < 4; j++) bfr[j] = *(const bf16x8*)&Bs[wn + j * 16 + l16][ka];
#pragma unroll
      for (int i = 0; i < 2; i++)
#pragma unroll
        for (int j = 0; j < 4; j++)
          acc[i][j] = __builtin_amdgcn_mfma_f32_16x16x32_bf16(af[i], bfr[j], acc[i][j], 0, 0, 0);
    }
    __syncthreads();
  }
#pragma unroll
  for (int j = 0; j < 4; j++) {
    const int colg = n0g + wn + j * 16 + l16;
    const int col = n0 + wn + j * 16 + l16;
    const float bv = b2f(bias3[colg]);
#pragma unroll
    for (int i = 0; i < 2; i++) {
#pragma unroll
      for (int r = 0; r < 4; r++) {
        const int row = m0 + wm + i * 16 + quad * 4 + r;
        out[(size_t)row * 1024 + col] = f2b(acc[i][j][r] + bv);
      }
    }
  }
}

// ---------------------------------------------------------------- LayerNorm (cleared)
__global__ __launch_bounds__(256) void ln_k(const float* __restrict__ Zraw,
                                            const __bf16* __restrict__ g,
                                            const __bf16* __restrict__ bb,
                                            __bf16* __restrict__ Z) {
  __shared__ float red[8];
  const int row = blockIdx.x, tid = threadIdx.x, lane = tid & 63, wv = tid >> 6;
  const float* x = Zraw + (size_t)row * 1024;
  float4 v = *(const float4*)&x[tid * 4];
  float s = v.x + v.y + v.z + v.w;
  float ss = v.x * v.x + v.y * v.y + v.z * v.z + v.w * v.w;
#pragma unroll
  for (int o = 32; o > 0; o >>= 1) {
    s += __shfl_down(s, o);
    ss += __shfl_down(ss, o);
  }
  if (lane == 0) { red[wv] = s; red[4 + wv] = ss; }
  __syncthreads();
  const float S = red[0] + red[1] + red[2] + red[3];
  const float SS = red[4] + red[5] + red[6] + red[7];
  const float mu = S * (1.f / 1024.f);
  const float var = SS * (1.f / 1024.f) - mu * mu;
  const float rstd = rsqrtf(var + 1e-5f);
  const int c = tid * 4;
  float xs[4] = {v.x, v.y, v.z, v.w};
  union { __bf16 h[4]; uint2 u; } pk;
#pragma unroll
  for (int i = 0; i < 4; i++)
    pk.h[i] = f2b((xs[i] - mu) * rstd * b2f(g[c + i]) + b2f(bb[c + i]));
  *(uint2*)&Z[(size_t)row * 1024 + c] = pk.u;
}

// ---------------------------------------------------------------- MFMA phasor (cleared r2)
__global__ __launch_bounds__(256) void phasor_mfma_k(const __bf16* __restrict__ Qf,
                                                     const __bf16* __restrict__ Rf,
                                                     const __bf16* __restrict__ Wphi,
                                                     const __bf16* __restrict__ bphi,
                                                     __bf16* __restrict__ Qc,
                                                     __bf16* __restrict__ Rc) {
  __shared__ __bf16 Qs[128][76];
  __shared__ __bf16 WT[64][76];
  const __bf16* in = blockIdx.y ? Rf : Qf;
  __bf16* out = blockIdx.y ? Rc : Qc;
  const int tid = threadIdx.x, lane = tid & 63, wv = tid >> 6;
  const int quad = lane >> 4, l16 = lane & 15;
  const size_t m0 = (size_t)blockIdx.x * 128;
  for (int i = tid; i < 1024; i += 256) {
    int r = i >> 3, c = (i & 7) * 8;
    *(int4*)&Qs[r][c] = *(const int4*)&in[(m0 + r) * 64 + c];
  }
  for (int i = tid; i < 4096; i += 256) WT[i & 63][i >> 6] = Wphi[i];
  __syncthreads();
  f32x4 acc[2][4] = {};
#pragma unroll
  for (int s = 0; s < 2; s++) {
    const int ka = s * 32 + quad * 8;
    bf16x8 bfr[4];
#pragma unroll
    for (int j = 0; j < 4; j++) bfr[j] = *(const bf16x8*)&WT[j * 16 + l16][ka];
#pragma unroll
    for (int i = 0; i < 2; i++) {
      const bf16x8 af = *(const bf16x8*)&Qs[wv * 32 + i * 16 + l16][ka];
#pragma unroll
      for (int j = 0; j < 4; j++)
        acc[i][j] = __builtin_amdgcn_mfma_f32_16x16x32_bf16(af, bfr[j], acc[i][j], 0, 0, 0);
    }
  }
#pragma unroll
  for (int i = 0; i < 2; i++)
#pragma unroll
    for (int j = 0; j < 4; j++) {
      const int col = j * 16 + l16;
      const float bj = b2f(bphi[col]);
#pragma unroll
      for (int r = 0; r < 4; r++) {
        const int row = wv * 32 + i * 16 + quad * 4 + r;
        const float phi = acc[i][j][r] + bj;
        float sn, cs;
        __sincosf(phi, &sn, &cs);
        const float qv = b2f(Qs[row][col]);
        const size_t ob = (m0 + row) * 128;
        out[ob + col] = f2b(qv * cs);
        out[ob + 64 + col] = f2b(qv * sn);
      }
    }
}

// ---------------------------------------------------------------- Hv transpose (cleared)
__global__ __launch_bounds__(256) void hvt_k(const __bf16* __restrict__ Hv,
                                             __bf16* __restrict__ HvT, int S) {
  __shared__ __bf16 t[64][72];
  const int tt = blockIdx.x * 64, h = blockIdx.y, b = blockIdx.z;
  const int tid = threadIdx.x;
  for (int i = tid; i < 512; i += 256) {
    int tok = i >> 3, dc = (i & 7) * 8;
    *(int4*)&t[tok][dc] = *(const int4*)&Hv[((size_t)(b * S + tt + tok) * 16 + h) * 64 + dc];
  }
  __syncthreads();
  for (int i = tid; i < 1024; i += 256) {
    int d = i >> 4, tc = (i & 15) * 4;
    union { __bf16 h4[4]; uint2 u; } pk;
    pk.h4[0] = t[tc + 0][d];
    pk.h4[1] = t[tc + 1][d];
    pk.h4[2] = t[tc + 2][d];
    pk.h4[3] = t[tc + 3][d];
    *(uint2*)&HvT[(((size_t)(b * 16 + h) * 64 + d) * S) + tt + tc] = pk.u;
  }
}

// ---------------------------------------------------------------- flash attention v4
// v4: q-tile 64 -> grid (S/64)*32 = 4 blocks/CU exactly (no tail), LDS 35840 B.
// Rs single-buffered (QK^T only), Hs double-buffered (PV). T14 async-STAGE split:
// loads issued at iter top (in flight across QK^T), ds_writes after mid-barrier,
// PV after. 2 barriers/iter. bpermute S^T redistribution unchanged (verified).
__global__ __launch_bounds__(256, 4) void attn_k(const __bf16* __restrict__ Qc,
                                                 const __bf16* __restrict__ Rc,
                                                 const __bf16* __restrict__ HvT,
                                                 __bf16* __restrict__ Aout, int S) {
  __shared__ __bf16 Rs[64][136];     // 17408 B
  __shared__ __bf16 Hs[2][64][72];   // 18432 B -> total 35840 B (4 blocks/CU)
  const int tid = threadIdx.x, lane = tid & 63, wv = tid >> 6;
  const int quad = lane >> 4, l16 = lane & 15;
  const int nblk = gridDim.x;   // (S/64)*32, % 8 == 0
  const int chunk = nblk >> 3;
  const int hb = blockIdx.x;
  const int lb = (hb & 7) * chunk + (hb >> 3);
  const int nx = nblk >> 5;     // = S/64
  const int x = lb % nx;
  const int rest = lb / nx;
  const int h = rest & 15, b = rest >> 4;
  const int q0 = x * 64;

  // Q fragments direct from global: wave rows q0 + wv*16 + l16
  bf16x8 qf[4];
  {
    const __bf16* qp = Qc + ((size_t)(b * S + q0 + wv * 16 + l16) * 16 + h) * 128 + quad * 8;
#pragma unroll
    for (int s = 0; s < 4; s++) qf[s] = *(const bf16x8*)(qp + s * 32);
  }

  const size_t rcb = ((size_t)b * S * 16 + h) * 128;
  const size_t hvb = (size_t)(b * 16 + h) * 64 * S;

  f32x4 oacc[4] = {};   // [jd]; col=q(l16), row=d(quad*4+r)
  float rssq = 0.f;
  const int nt = S >> 6;

  // prologue: stage tile 0 (Rs + Hs[0])
  for (int ii = tid; ii < 1024; ii += 256) {
    int r_ = ii >> 4, c_ = (ii & 15) * 8;
    *(int4*)&Rs[r_][c_] = *(const int4*)&Rc[rcb + (size_t)r_ * 2048 + c_];
  }
  for (int ii = tid; ii < 512; ii += 256) {
    int d_ = ii >> 3, c_ = (ii & 7) * 8;
    *(int4*)&Hs[0][d_][c_] = *(const int4*)&HvT[hvb + (size_t)d_ * S + c_];
  }
  __syncthreads();

  const int srcA = ((quad & 1) << 1) | (quad >> 1);
  const int adA = ((srcA << 4) | l16) << 2;
  const int adB = (((srcA ^ 1) << 4) | l16) << 2;
  const bool par = (quad & 1) != 0;
  const bool hi = (quad >> 1) != 0;

  for (int it = 0; it < nt; ++it) {
    const int cur = it & 1;
    const bool pf = (it + 1 < nt);
    // ---- T14 load-phase for tile it+1 (stays in flight across QK^T)
    int4 rreg[4], hreg[2];
    if (pf) {
      const int t0 = (it + 1) * 64;
#pragma unroll
      for (int u = 0; u < 4; u++) {
        const int ii = tid + u * 256;
        const int r_ = ii >> 4, c_ = (ii & 15) * 8;
        rreg[u] = *(const int4*)&Rc[rcb + (size_t)(t0 + r_) * 2048 + c_];
      }
#pragma unroll
      for (int u = 0; u < 2; u++) {
        const int ii = tid + u * 256;
        const int d_ = ii >> 3, c_ = (ii & 7) * 8;
        hreg[u] = *(const int4*)&HvT[hvb + (size_t)d_ * S + t0 + c_];
      }
    }

    // ---- QK^T (swapped): sacc[jt] rows = kv (jt*16 + quad*4 + r), cols = q (l16)
    f32x4 sacc[4] = {};
#pragma unroll
    for (int s = 0; s < 4; s++) {
      const int ka = s * 32 + quad * 8;
#pragma unroll
      for (int jt = 0; jt < 4; jt++) {
        const bf16x8 rf = *(const bf16x8*)&Rs[jt * 16 + l16][ka];
        sacc[jt] = __builtin_amdgcn_mfma_f32_16x16x32_bf16(rf, qf[s], sacc[jt], 0, 0, 0);
      }
    }

    // ---- rssq (exact f32) + pack S to bf16 pairs
    unsigned pk[4][2];
#pragma unroll
    for (int jt = 0; jt < 4; jt++) {
      rssq += sacc[jt][0] * sacc[jt][0] + sacc[jt][1] * sacc[jt][1] +
              sacc[jt][2] * sacc[jt][2] + sacc[jt][3] * sacc[jt][3];
      union { __bf16 h2[2]; unsigned u; } p0, p1;
      p0.h2[0] = f2b(sacc[jt][0]); p0.h2[1] = f2b(sacc[jt][1]);
      p1.h2[0] = f2b(sacc[jt][2]); p1.h2[1] = f2b(sacc[jt][3]);
      pk[jt][0] = p0.u; pk[jt][1] = p1.u;
    }

    __syncthreads();  // all waves' QK^T Rs reads complete

    // ---- T14 write-phase: Rs (tile it+1) + Hs[cur^1]
    if (pf) {
#pragma unroll
      for (int u = 0; u < 4; u++) {
        const int ii = tid + u * 256;
        const int r_ = ii >> 4, c_ = (ii & 15) * 8;
        *(int4*)&Rs[r_][c_] = rreg[u];
      }
#pragma unroll
      for (int u = 0; u < 2; u++) {
        const int ii = tid + u * 256;
        const int d_ = ii >> 3, c_ = (ii & 7) * 8;
        *(int4*)&Hs[cur ^ 1][d_][c_] = hreg[u];
      }
    }

    // ---- PV on Hs[cur]: O^T += HvT-frag (rows=d) x S^T-frag (cols=q, in-register)
#pragma unroll
    for (int s2 = 0; s2 < 2; s2++) {
      bf16x8 hf[4];
#pragma unroll
      for (int jd = 0; jd < 4; jd++)
        hf[jd] = *(const bf16x8*)&Hs[cur][jd * 16 + l16][s2 * 32 + quad * 8];
      const int jA = 2 * s2, jB = 2 * s2 + 1;
      const unsigned o0 = par ? pk[jB][0] : pk[jA][0];
      const unsigned o1 = par ? pk[jB][1] : pk[jA][1];
      const unsigned o2 = par ? pk[jA][0] : pk[jB][0];
      const unsigned o3 = par ? pk[jA][1] : pk[jB][1];
      const unsigned r0 = (unsigned)__builtin_amdgcn_ds_bpermute(adA, (int)o0);
      const unsigned r1 = (unsigned)__builtin_amdgcn_ds_bpermute(adA, (int)o1);
      const unsigned r2 = (unsigned)__builtin_amdgcn_ds_bpermute(adB, (int)o2);
      const unsigned r3 = (unsigned)__builtin_amdgcn_ds_bpermute(adB, (int)o3);
      union { unsigned u[4]; bf16x8 v; } bw;
      bw.u[0] = hi ? r2 : r0;
      bw.u[1] = hi ? r3 : r1;
      bw.u[2] = hi ? r0 : r2;
      bw.u[3] = hi ? r1 : r3;
#pragma unroll
      for (int jd = 0; jd < 4; jd++)
        oacc[jd] = __builtin_amdgcn_mfma_f32_16x16x32_bf16(hf[jd], bw.v, oacc[jd], 0, 0, 0);
    }
    __syncthreads();  // Rs/Hs writes visible before next iter's reads
  }

  // ---- normalize + packed store
  {
    float t = rssq;
    t += __shfl_xor(t, 16);
    t += __shfl_xor(t, 32);
    const float inv = 1.0f / fmaxf(sqrtf(t), 1e-12f);
    const size_t orow = (size_t)(b * S + q0 + wv * 16 + l16) * 1024 + h * 64;
#pragma unroll
    for (int jd = 0; jd < 4; jd++) {
      union { __bf16 h4[4]; uint2 u2; } o;
#pragma unroll
      for (int r = 0; r < 4; r++) o.h4[r] = f2b(oacc[jd][r] * inv);
      *(uint2*)&Aout[orow + jd * 16 + quad * 4] = o.u2;
    }
  }
}

// ---------------------------------------------------------------- launch
extern "C" void kernel_launch(void* const* d_in, const int* in_sizes, int n_in,
                              void* d_out, int out_size, void* d_ws, size_t ws_size,
                              hipStream_t stream) {
  const void* query = d_in[0];
  const void* Wz = d_in[3];
  const void* bz = d_in[4];
  const void* ln_g = d_in[5];
  const void* ln_b = d_in[6];
  const void* Wq = d_in[7];
  const void* bq = d_in[8];
  const void* Wr = d_in[9];
  const void* br = d_in[10];
  const void* Wh = d_in[11];
  const void* bh = d_in[12];
  const void* Wphi = d_in[13];
  const void* bphi = d_in[14];
  const void* Wo = d_in[15];
  const void* bo = d_in[16];

  const int n_q = in_sizes[0];   // B*S*1024
  const int Srows = n_q >> 10;   // B*S
  const int S = Srows >> 1;      // B = 2

  char* ws = (char*)d_ws;
  const size_t MB = 1024 * 1024;

  int* mode = (int*)(ws);
  __bf16* sv = (__bf16*)(ws + 4096);
  __bf16* bz_c   = sv + 0 * 4096;
  __bf16* lng_c  = sv + 1 * 4096;
  __bf16* lnb_c  = sv + 2 * 4096;
  __bf16* bo_c   = sv + 3 * 4096;
  __bf16* bphi_c = sv + 4 * 4096;
  __bf16* wphi_c = sv + 5 * 4096;   // 4096 elems
  __bf16* bqrh   = sv + 6 * 4096;   // 3072 elems
  __bf16* WzT    = (__bf16*)(ws + 1 * MB);   // 2 MB
  __bf16* WoT    = (__bf16*)(ws + 3 * MB);   // 2 MB
  __bf16* WqrhT  = (__bf16*)(ws + 5 * MB);   // 6 MB
  float*  Zraw   = (float*) (ws + 11 * MB);  // 16 MB, dead after ln
  __bf16* Z      = (__bf16*)(ws + 27 * MB);  // 8 MB, dead after qrh gemm
  __bf16* Qf     = (__bf16*)(ws + 35 * MB);  // 8 MB, dead after phasor Q
  __bf16* Rf     = (__bf16*)(ws + 43 * MB);  // 8 MB, dead after phasor R
  __bf16* Hv     = (__bf16*)(ws + 51 * MB);  // 8 MB, dead after hvt
  __bf16* Rc     = (__bf16*)(ws + 59 * MB);  // 16 MB (top = 75 MB, proven safe)
  __bf16* Qc     = (__bf16*)(ws + 11 * MB);  // 16 MB over dead Zraw
  __bf16* HvT    = (__bf16*)(ws + 27 * MB);  // 8 MB over dead Z
  __bf16* Aout   = (__bf16*)(ws + 35 * MB);  // 8 MB over dead Qf

  dim3 blk(256);
  detect_k<<<1, 64, 0, stream>>>((const unsigned short*)query, mode);

  CvtJobs cj;
  cj.src[0] = bz;   cj.dst[0] = bz_c;
  cj.src[1] = ln_g; cj.dst[1] = lng_c;
  cj.src[2] = ln_b; cj.dst[2] = lnb_c;
  cj.src[3] = bo;   cj.dst[3] = bo_c;
  cj.src[4] = bphi; cj.dst[4] = bphi_c;
  cj.src[5] = Wphi; cj.dst[5] = wphi_c;
  cj.src[6] = bq;   cj.dst[6] = bqrh;
  cj.src[7] = br;   cj.dst[7] = bqrh + 1024;
  cj.src[8] = bh;   cj.dst[8] = bqrh + 2048;
  cvt_all_k<<<12, blk, 0, stream>>>(cj, mode);

  TJobs tj;
  tj.src[0] = Wz; tj.dst[0] = WzT;
  tj.src[1] = Wo; tj.dst[1] = WoT;
  tj.src[2] = Wq; tj.dst[2] = WqrhT;
  tj.src[3] = Wr; tj.dst[3] = WqrhT + 1024 * 1024;
  tj.src[4] = Wh; tj.dst[4] = WqrhT + 2 * 1024 * 1024;
  tcvt_all_k<<<dim3(16, 16, 5), blk, 0, stream>>>(tj, mode);

  dim3 ggrid(8, Srows / 64);   // BM=64 x BN=128 tiles -> 512 blocks (2/CU)
  gemm64m_k<true, true><<<ggrid, blk, 0, stream>>>(query, WzT, bz_c, (void*)Zraw,
                                                   Srows, 1024, 1024, mode);
  ln_k<<<Srows, blk, 0, stream>>>(Zraw, lng_c, lnb_c, Z);
  qrh64_k<<<dim3(24, Srows / 64), blk, 0, stream>>>(Z, WqrhT, bqrh, Qf, Rf, Hv, Srows);
  phasor_mfma_k<<<dim3((Srows * 16) / 128, 2), blk, 0, stream>>>(Qf, Rf, wphi_c, bphi_c, Qc, Rc);
  hvt_k<<<dim3(S / 64, 16, 2), blk, 0, stream>>>(Hv, HvT, S);
  attn_k<<<dim3((S / 64) * 32), blk, 0, stream>>>(Qc, Rc, HvT, Aout, S);
  gemm64m_k<true, false><<<ggrid, blk, 0, stream>>>(Aout, WoT, bo_c, d_out,
                                                    Srows, 1024, 1024, mode);
}

// Round 4
// 442.371 us; speedup vs baseline: 1.3632x; 1.3632x over previous
//
#include <hip/hip_runtime.h>

#define DEV __device__ __forceinline__

typedef __bf16 bf16x8 __attribute__((ext_vector_type(8)));
typedef float f32x4 __attribute__((ext_vector_type(4)));

DEV float b2f(__bf16 v) { return (float)v; }
DEV __bf16 f2b(float v) { return (__bf16)v; }

DEV void gload16(const __bf16* g, __bf16* l) {
  __builtin_amdgcn_global_load_lds((const __attribute__((address_space(1))) unsigned*)g,
                                   (__attribute__((address_space(3))) unsigned*)l, 16, 0, 0);
}

// ---------------------------------------------------------------- dtype detect (3-way)
__global__ void detect_k(const unsigned short* __restrict__ q, int* __restrict__ mode) {
  const int lane = threadIdx.x & 63;
  int cntNaN = 0, cntSmall = 0;
  for (int i = lane; i < 16384; i += 64) {
    const unsigned ef = (q[i] >> 7) & 0xFF;
    if (ef == 0xFF) cntNaN++;
    if (ef < 0x70) cntSmall++;
  }
#pragma unroll
  for (int o = 32; o > 0; o >>= 1) {
    cntNaN += __shfl_down(cntNaN, o);
    cntSmall += __shfl_down(cntSmall, o);
  }
  if (lane == 0) *mode = (cntNaN >= 4) ? 1 : ((cntSmall > 2000) ? 2 : 0);
}

// ---------------------------------------------------------------- fused small-vector convert
struct CvtJobs {
  const void* src[9];
  __bf16* dst[9];
};
__global__ __launch_bounds__(256) void cvt_all_k(CvtJobs J, const int* __restrict__ mode) {
  const int bb = blockIdx.x;
  int job, off;
  if (bb < 4) { job = bb; off = 0; }
  else if (bb == 4) { job = 4; off = 0; }
  else if (bb < 9) { job = 5; off = (bb - 5) * 1024; }
  else { job = 6 + (bb - 9); off = 0; }
  const int n = (job == 4) ? 64 : (job == 5) ? 4096 : 1024;
  const int m = *mode;
  const void* s = J.src[job];
  __bf16* d = J.dst[job];
  const int rem = n - off;
  const int cnt = rem > 1024 ? 1024 : rem;
  for (int i = threadIdx.x; i < cnt; i += 256) {
    const int idx = off + i;
    const float v = (m == 1) ? ((const float*)s)[idx]
                  : (m == 2) ? (float)((const _Float16*)s)[idx]
                             : b2f(((const __bf16*)s)[idx]);
    d[idx] = f2b(v);
  }
}

// ---------------------------------------------------------------- fused LDS-tiled transpose+convert
struct TJobs {
  const void* src[5];
  __bf16* dst[5];
};
__global__ __launch_bounds__(256) void tcvt_all_k(TJobs J, const int* __restrict__ mode) {
  __shared__ __bf16 tile[64][68];
  const void* in = J.src[blockIdx.z];
  __bf16* out = J.dst[blockIdx.z];
  const int c0 = blockIdx.x * 64, r0 = blockIdx.y * 64;
  const int tid = threadIdx.x;
  const int m = *mode;
  for (int i = tid; i < 64 * 16; i += 256) {
    int r = i >> 4, cc = (i & 15) * 4;
    const size_t base = (size_t)(r0 + r) * 1024 + c0 + cc;
    if (m == 1) {
      float4 v = *(const float4*)((const float*)in + base);
      tile[r][cc + 0] = f2b(v.x);
      tile[r][cc + 1] = f2b(v.y);
      tile[r][cc + 2] = f2b(v.z);
      tile[r][cc + 3] = f2b(v.w);
    } else if (m == 2) {
      const _Float16* p = (const _Float16*)in + base;
      tile[r][cc + 0] = f2b((float)p[0]);
      tile[r][cc + 1] = f2b((float)p[1]);
      tile[r][cc + 2] = f2b((float)p[2]);
      tile[r][cc + 3] = f2b((float)p[3]);
    } else {
      *(uint2*)&tile[r][cc] = *(const uint2*)((const __bf16*)in + base);
    }
  }
  __syncthreads();
  for (int i = tid; i < 64 * 16; i += 256) {
    int c = i >> 4, rr = (i & 15) * 4;
    union { __bf16 h[4]; uint2 u; } pk;
    pk.h[0] = tile[rr + 0][c];
    pk.h[1] = tile[rr + 1][c];
    pk.h[2] = tile[rr + 2][c];
    pk.h[3] = tile[rr + 3][c];
    *(uint2*)&out[(size_t)(c0 + c) * 1024 + r0 + rr] = pk.u;
  }
}

// ---------------------------------------------------------------- GEMM BM=64 x BN=128
template <bool OUT_F32, bool A_CHK>
__global__ __launch_bounds__(256) void gemm64m_k(const void* __restrict__ Av,
                                                 const __bf16* __restrict__ BT,
                                                 const __bf16* __restrict__ bias,
                                                 void* __restrict__ Cout,
                                                 int M, int N, int K,
                                                 const int* __restrict__ mode) {
  __shared__ __bf16 As[64][72];
  __shared__ __bf16 Bs[128][72];
  const int tid = threadIdx.x, lane = tid & 63, wv = tid >> 6;
  const int quad = lane >> 4, l16 = lane & 15;
  const int m0 = blockIdx.y * 64, n0 = blockIdx.x * 128;
  const int wm = (wv >> 1) * 32, wn = (wv & 1) * 64;
  int am = 0;
  if constexpr (A_CHK) am = *mode;
  f32x4 acc[2][4] = {};
  for (int k0 = 0; k0 < K; k0 += 64) {
    if (A_CHK && am == 1) {
      for (int i = tid; i < 512; i += 256) {
        int r = i >> 3, kc = (i & 7) * 8;
        const float* ap = (const float*)Av + (size_t)(m0 + r) * K + k0 + kc;
        float4 v0 = *(const float4*)ap, v1 = *(const float4*)(ap + 4);
        union { __bf16 h[8]; int4 u; } pk;
        pk.h[0] = f2b(v0.x); pk.h[1] = f2b(v0.y); pk.h[2] = f2b(v0.z); pk.h[3] = f2b(v0.w);
        pk.h[4] = f2b(v1.x); pk.h[5] = f2b(v1.y); pk.h[6] = f2b(v1.z); pk.h[7] = f2b(v1.w);
        *(int4*)&As[r][kc] = pk.u;
      }
    } else if (A_CHK && am == 2) {
      for (int i = tid; i < 512; i += 256) {
        int r = i >> 3, kc = (i & 7) * 8;
        const _Float16* ap = (const _Float16*)Av + (size_t)(m0 + r) * K + k0 + kc;
        union { __bf16 h[8]; int4 u; } pk;
#pragma unroll
        for (int t = 0; t < 8; t++) pk.h[t] = f2b((float)ap[t]);
        *(int4*)&As[r][kc] = pk.u;
      }
    } else {
      for (int i = tid; i < 512; i += 256) {
        int r = i >> 3, kc = (i & 7) * 8;
        *(int4*)&As[r][kc] = *(const int4*)((const __bf16*)Av + (size_t)(m0 + r) * K + k0 + kc);
      }
    }
    for (int i = tid; i < 1024; i += 256) {
      int r = i >> 3, kc = (i & 7) * 8;
      *(int4*)&Bs[r][kc] = *(const int4*)&BT[(size_t)(n0 + r) * K + k0 + kc];
    }
    __syncthreads();
#pragma unroll
    for (int ks = 0; ks < 64; ks += 32) {
      const int ka = ks + quad * 8;
      bf16x8 af[2], bfr[4];
#pragma unroll
      for (int i = 0; i < 2; i++) af[i] = *(const bf16x8*)&As[wm + i * 16 + l16][ka];
#pragma unroll
      for (int j = 0; j < 4; j++) bfr[j] = *(const bf16x8*)&Bs[wn + j * 16 + l16][ka];
#pragma unroll
      for (int i = 0; i < 2; i++)
#pragma unroll
        for (int j = 0; j < 4; j++)
          acc[i][j] = __builtin_amdgcn_mfma_f32_16x16x32_bf16(af[i], bfr[j], acc[i][j], 0, 0, 0);
    }
    __syncthreads();
  }
#pragma unroll
  for (int j = 0; j < 4; j++) {
    const int col = n0 + wn + j * 16 + l16;
    const float bv = b2f(bias[col]);
#pragma unroll
    for (int i = 0; i < 2; i++) {
#pragma unroll
      for (int r = 0; r < 4; r++) {
        const int row = m0 + wm + i * 16 + quad * 4 + r;
        const float v = acc[i][j][r] + bv;
        if (OUT_F32)
          ((float*)Cout)[(size_t)row * N + col] = v;
        else
          ((__bf16*)Cout)[(size_t)row * N + col] = f2b(v);
      }
    }
  }
}

// ---------------------------------------------------------------- fused Q/R/H GEMM, BM=64 x BN=128
__global__ __launch_bounds__(256) void qrh64_k(const __bf16* __restrict__ A,
                                               const __bf16* __restrict__ BT3,
                                               const __bf16* __restrict__ bias3,
                                               __bf16* __restrict__ Qf,
                                               __bf16* __restrict__ Rf,
                                               __bf16* __restrict__ Hv,
                                               int M) {
  __shared__ __bf16 As[64][72];
  __shared__ __bf16 Bs[128][72];
  const int tid = threadIdx.x, lane = tid & 63, wv = tid >> 6;
  const int quad = lane >> 4, l16 = lane & 15;
  const int m0 = blockIdx.y * 64, n0g = blockIdx.x * 128;
  const int which = n0g >> 10, n0 = n0g & 1023;
  __bf16* out = (which == 0) ? Qf : (which == 1) ? Rf : Hv;
  const int wm = (wv >> 1) * 32, wn = (wv & 1) * 64;
  f32x4 acc[2][4] = {};
  for (int k0 = 0; k0 < 1024; k0 += 64) {
    for (int i = tid; i < 512; i += 256) {
      int r = i >> 3, kc = (i & 7) * 8;
      *(int4*)&As[r][kc] = *(const int4*)&A[(size_t)(m0 + r) * 1024 + k0 + kc];
    }
    for (int i = tid; i < 1024; i += 256) {
      int r = i >> 3, kc = (i & 7) * 8;
      *(int4*)&Bs[r][kc] = *(const int4*)&BT3[(size_t)(n0g + r) * 1024 + k0 + kc];
    }
    __syncthreads();
#pragma unroll
    for (int ks = 0; ks < 64; ks += 32) {
      const int ka = ks + quad * 8;
      bf16x8 af[2], bfr[4];
#pragma unroll
      for (int i = 0; i < 2; i++) af[i] = *(const bf16x8*)&As[wm + i * 16 + l16][ka];
#pragma unroll
      for (int j = 0; j < 4; j++) bfr[j] = *(const bf16x8*)&Bs[wn + j * 16 + l16][ka];
#pragma unroll
      for (int i = 0; i < 2; i++)
#pragma unroll
        for (int j = 0; j < 4; j++)
          acc[i][j] = __builtin_amdgcn_mfma_f32_16x16x32_bf16(af[i], bfr[j], acc[i][j], 0, 0, 0);
    }
    __syncthreads();
  }
#pragma unroll
  for (int j = 0; j < 4; j++) {
    const int colg = n0g + wn + j * 16 + l16;
    const int col = n0 + wn + j * 16 + l16;
    const float bv = b2f(bias3[colg]);
#pragma unroll
    for (int i = 0; i < 2; i++) {
#pragma unroll
      for (int r = 0; r < 4; r++) {
        const int row = m0 + wm + i * 16 + quad * 4 + r;
        out[(size_t)row * 1024 + col] = f2b(acc[i][j][r] + bv);
      }
    }
  }
}

// ---------------------------------------------------------------- LayerNorm (cleared)
__global__ __launch_bounds__(256) void ln_k(const float* __restrict__ Zraw,
                                            const __bf16* __restrict__ g,
                                            const __bf16* __restrict__ bb,
                                            __bf16* __restrict__ Z) {
  __shared__ float red[8];
  const int row = blockIdx.x, tid = threadIdx.x, lane = tid & 63, wv = tid >> 6;
  const float* x = Zraw + (size_t)row * 1024;
  float4 v = *(const float4*)&x[tid * 4];
  float s = v.x + v.y + v.z + v.w;
  float ss = v.x * v.x + v.y * v.y + v.z * v.z + v.w * v.w;
#pragma unroll
  for (int o = 32; o > 0; o >>= 1) {
    s += __shfl_down(s, o);
    ss += __shfl_down(ss, o);
  }
  if (lane == 0) { red[wv] = s; red[4 + wv] = ss; }
  __syncthreads();
  const float S = red[0] + red[1] + red[2] + red[3];
  const float SS = red[4] + red[5] + red[6] + red[7];
  const float mu = S * (1.f / 1024.f);
  const float var = SS * (1.f / 1024.f) - mu * mu;
  const float rstd = rsqrtf(var + 1e-5f);
  const int c = tid * 4;
  float xs[4] = {v.x, v.y, v.z, v.w};
  union { __bf16 h[4]; uint2 u; } pk;
#pragma unroll
  for (int i = 0; i < 4; i++)
    pk.h[i] = f2b((xs[i] - mu) * rstd * b2f(g[c + i]) + b2f(bb[c + i]));
  *(uint2*)&Z[(size_t)row * 1024 + c] = pk.u;
}

// ---------------------------------------------------------------- MFMA phasor (cleared r2)
__global__ __launch_bounds__(256) void phasor_mfma_k(const __bf16* __restrict__ Qf,
                                                     const __bf16* __restrict__ Rf,
                                                     const __bf16* __restrict__ Wphi,
                                                     const __bf16* __restrict__ bphi,
                                                     __bf16* __restrict__ Qc,
                                                     __bf16* __restrict__ Rc) {
  __shared__ __bf16 Qs[128][76];
  __shared__ __bf16 WT[64][76];
  const __bf16* in = blockIdx.y ? Rf : Qf;
  __bf16* out = blockIdx.y ? Rc : Qc;
  const int tid = threadIdx.x, lane = tid & 63, wv = tid >> 6;
  const int quad = lane >> 4, l16 = lane & 15;
  const size_t m0 = (size_t)blockIdx.x * 128;
  for (int i = tid; i < 1024; i += 256) {
    int r = i >> 3, c = (i & 7) * 8;
    *(int4*)&Qs[r][c] = *(const int4*)&in[(m0 + r) * 64 + c];
  }
  for (int i = tid; i < 4096; i += 256) WT[i & 63][i >> 6] = Wphi[i];
  __syncthreads();
  f32x4 acc[2][4] = {};
#pragma unroll
  for (int s = 0; s < 2; s++) {
    const int ka = s * 32 + quad * 8;
    bf16x8 bfr[4];
#pragma unroll
    for (int j = 0; j < 4; j++) bfr[j] = *(const bf16x8*)&WT[j * 16 + l16][ka];
#pragma unroll
    for (int i = 0; i < 2; i++) {
      const bf16x8 af = *(const bf16x8*)&Qs[wv * 32 + i * 16 + l16][ka];
#pragma unroll
      for (int j = 0; j < 4; j++)
        acc[i][j] = __builtin_amdgcn_mfma_f32_16x16x32_bf16(af, bfr[j], acc[i][j], 0, 0, 0);
    }
  }
#pragma unroll
  for (int i = 0; i < 2; i++)
#pragma unroll
    for (int j = 0; j < 4; j++) {
      const int col = j * 16 + l16;
      const float bj = b2f(bphi[col]);
#pragma unroll
      for (int r = 0; r < 4; r++) {
        const int row = wv * 32 + i * 16 + quad * 4 + r;
        const float phi = acc[i][j][r] + bj;
        float sn, cs;
        __sincosf(phi, &sn, &cs);
        const float qv = b2f(Qs[row][col]);
        const size_t ob = (m0 + row) * 128;
        out[ob + col] = f2b(qv * cs);
        out[ob + 64 + col] = f2b(qv * sn);
      }
    }
}

// ---------------------------------------------------------------- Hv transpose (cleared)
__global__ __launch_bounds__(256) void hvt_k(const __bf16* __restrict__ Hv,
                                             __bf16* __restrict__ HvT, int S) {
  __shared__ __bf16 t[64][72];
  const int tt = blockIdx.x * 64, h = blockIdx.y, b = blockIdx.z;
  const int tid = threadIdx.x;
  for (int i = tid; i < 512; i += 256) {
    int tok = i >> 3, dc = (i & 7) * 8;
    *(int4*)&t[tok][dc] = *(const int4*)&Hv[((size_t)(b * S + tt + tok) * 16 + h) * 64 + dc];
  }
  __syncthreads();
  for (int i = tid; i < 1024; i += 256) {
    int d = i >> 4, tc = (i & 15) * 4;
    union { __bf16 h4[4]; uint2 u; } pk;
    pk.h4[0] = t[tc + 0][d];
    pk.h4[1] = t[tc + 1][d];
    pk.h4[2] = t[tc + 2][d];
    pk.h4[3] = t[tc + 3][d];
    *(uint2*)&HvT[(((size_t)(b * 16 + h) * 64 + d) * S) + tt + tc] = pk.u;
  }
}

// ---------------------------------------------------------------- flash attention v5
// v5: v4 compute core (verified) + global_load_lds double-buffered staging.
// LDS linear (gload_lds requires it); bank conflicts fixed by 16B-chunk XOR
// swizzle applied to BOTH global source addr (per-lane constant) and LDS reads
// (key = l16&7, lane-constant). 1 barrier/iter; loads in flight across full
// compute phase. LDS 48 KB -> 3 blocks/CU; no reg prefetch (v4 spill fix).
__global__ __launch_bounds__(256) void attn_k(const __bf16* __restrict__ Qc,
                                              const __bf16* __restrict__ Rc,
                                              const __bf16* __restrict__ HvT,
                                              __bf16* __restrict__ Aout, int S) {
  __shared__ __bf16 Rs[2][64 * 128];  // 32768 B, linear
  __shared__ __bf16 Hs[2][64 * 64];   // 16384 B, linear -> total 49152 B
  const int tid = threadIdx.x, lane = tid & 63, wv = tid >> 6;
  const int quad = lane >> 4, l16 = lane & 15;
  const int nblk = gridDim.x;   // (S/64)*32, % 8 == 0
  const int chunk = nblk >> 3;
  const int hb = blockIdx.x;
  const int lb = (hb & 7) * chunk + (hb >> 3);
  const int nx = nblk >> 5;     // = S/64
  const int x = lb % nx;
  const int rest = lb / nx;
  const int h = rest & 15, b = rest >> 4;
  const int q0 = x * 64;

  // Q fragments direct from global: wave rows q0 + wv*16 + l16
  bf16x8 qf[4];
  {
    const __bf16* qp = Qc + ((size_t)(b * S + q0 + wv * 16 + l16) * 16 + h) * 128 + quad * 8;
#pragma unroll
    for (int s = 0; s < 4; s++) qf[s] = *(const bf16x8*)(qp + s * 32);
  }

  const size_t rcb = ((size_t)b * S * 16 + h) * 128;   // Rc[rcb + tok*2048 + c]
  const size_t hvb = (size_t)(b * 16 + h) * 64 * S;    // HvT[hvb + d*S + tok]

  // staging source offsets (pre-swizzled, per-lane constants)
  int rs_src[4], hs_src[2];
#pragma unroll
  for (int u = 0; u < 4; u++) {
    const int r = 4 * (wv * 4 + u) + (lane >> 4);      // Rs row 0..63
    rs_src[u] = r * 2048 + (((lane & 15) ^ (r & 7)) * 8);
  }
#pragma unroll
  for (int u = 0; u < 2; u++) {
    const int row = 8 * (wv * 2 + u) + (lane >> 3);    // Hs row (=d) 0..63
    hs_src[u] = row * S + (((lane & 7) ^ (row & 7)) * 8);
  }

#define STAGE(BUF, TILE)                                                        \
  {                                                                             \
    const __bf16* rc_ = Rc + rcb + (size_t)(TILE) * 64 * 2048;                  \
    const __bf16* hv_ = HvT + hvb + (TILE) * 64;                                \
    _Pragma("unroll")                                                           \
    for (int u = 0; u < 4; u++)                                                 \
      gload16(rc_ + rs_src[u], &Rs[BUF][(wv * 4 + u) * 512]);                   \
    _Pragma("unroll")                                                           \
    for (int u = 0; u < 2; u++)                                                 \
      gload16(hv_ + hs_src[u], &Hs[BUF][(wv * 2 + u) * 512]);                   \
  }

  f32x4 oacc[4] = {};   // [jd]; col=q(l16), row=d(quad*4+r)
  float rssq = 0.f;
  const int nt = S >> 6;

  STAGE(0, 0);
  __syncthreads();

  const int srcA = ((quad & 1) << 1) | (quad >> 1);
  const int adA = ((srcA << 4) | l16) << 2;
  const int adB = (((srcA ^ 1) << 4) | l16) << 2;
  const bool par = (quad & 1) != 0;
  const bool hi = (quad >> 1) != 0;
  const int key = l16 & 7;   // read-side swizzle key (lane-constant)

  for (int it = 0; it < nt; ++it) {
    const int cur = it & 1;
    if (it + 1 < nt) STAGE(cur ^ 1, it + 1);   // in flight across full compute

    // ---- QK^T (swapped): sacc[jt] rows = kv (jt*16 + quad*4 + r), cols = q (l16)
    f32x4 sacc[4] = {};
#pragma unroll
    for (int s = 0; s < 4; s++) {
      const int co = ((4 * s + quad) ^ key) * 8;   // swizzled 16B chunk
#pragma unroll
      for (int jt = 0; jt < 4; jt++) {
        const bf16x8 rf = *(const bf16x8*)&Rs[cur][(jt * 16 + l16) * 128 + co];
        sacc[jt] = __builtin_amdgcn_mfma_f32_16x16x32_bf16(rf, qf[s], sacc[jt], 0, 0, 0);
      }
    }

    // ---- rssq (exact f32) + pack S to bf16 pairs
    unsigned pk[4][2];
#pragma unroll
    for (int jt = 0; jt < 4; jt++) {
      rssq += sacc[jt][0] * sacc[jt][0] + sacc[jt][1] * sacc[jt][1] +
              sacc[jt][2] * sacc[jt][2] + sacc[jt][3] * sacc[jt][3];
      union { __bf16 h2[2]; unsigned u; } p0, p1;
      p0.h2[0] = f2b(sacc[jt][0]); p0.h2[1] = f2b(sacc[jt][1]);
      p1.h2[0] = f2b(sacc[jt][2]); p1.h2[1] = f2b(sacc[jt][3]);
      pk[jt][0] = p0.u; pk[jt][1] = p1.u;
    }

    // ---- PV: O^T += HvT-frag (rows=d) x S^T-frag (cols=q, in-register bpermute)
#pragma unroll
    for (int s2 = 0; s2 < 2; s2++) {
      bf16x8 hf[4];
      const int co2 = ((4 * s2 + quad) ^ key) * 8;
#pragma unroll
      for (int jd = 0; jd < 4; jd++)
        hf[jd] = *(const bf16x8*)&Hs[cur][(jd * 16 + l16) * 64 + co2];
      const int jA = 2 * s2, jB = 2 * s2 + 1;
      const unsigned o0 = par ? pk[jB][0] : pk[jA][0];
      const unsigned o1 = par ? pk[jB][1] : pk[jA][1];
      const unsigned o2 = par ? pk[jA][0] : pk[jB][0];
      const unsigned o3 = par ? pk[jA][1] : pk[jB][1];
      const unsigned r0 = (unsigned)__builtin_amdgcn_ds_bpermute(adA, (int)o0);
      const unsigned r1 = (unsigned)__builtin_amdgcn_ds_bpermute(adA, (int)o1);
      const unsigned r2 = (unsigned)__builtin_amdgcn_ds_bpermute(adB, (int)o2);
      const unsigned r3 = (unsigned)__builtin_amdgcn_ds_bpermute(adB, (int)o3);
      union { unsigned u[4]; bf16x8 v; } bw;
      bw.u[0] = hi ? r2 : r0;
      bw.u[1] = hi ? r3 : r1;
      bw.u[2] = hi ? r0 : r2;
      bw.u[3] = hi ? r1 : r3;
#pragma unroll
      for (int jd = 0; jd < 4; jd++)
        oacc[jd] = __builtin_amdgcn_mfma_f32_16x16x32_bf16(hf[jd], bw.v, oacc[jd], 0, 0, 0);
    }
    __syncthreads();  // drains vmcnt (gloads landed) + closes buf reads
  }
#undef STAGE

  // ---- normalize + packed store
  {
    float t = rssq;
    t += __shfl_xor(t, 16);
    t += __shfl_xor(t, 32);
    const float inv = 1.0f / fmaxf(sqrtf(t), 1e-12f);
    const size_t orow = (size_t)(b * S + q0 + wv * 16 + l16) * 1024 + h * 64;
#pragma unroll
    for (int jd = 0; jd < 4; jd++) {
      union { __bf16 h4[4]; uint2 u2; } o;
#pragma unroll
      for (int r = 0; r < 4; r++) o.h4[r] = f2b(oacc[jd][r] * inv);
      *(uint2*)&Aout[orow + jd * 16 + quad * 4] = o.u2;
    }
  }
}

// ---------------------------------------------------------------- launch
extern "C" void kernel_launch(void* const* d_in, const int* in_sizes, int n_in,
                              void* d_out, int out_size, void* d_ws, size_t ws_size,
                              hipStream_t stream) {
  const void* query = d_in[0];
  const void* Wz = d_in[3];
  const void* bz = d_in[4];
  const void* ln_g = d_in[5];
  const void* ln_b = d_in[6];
  const void* Wq = d_in[7];
  const void* bq = d_in[8];
  const void* Wr = d_in[9];
  const void* br = d_in[10];
  const void* Wh = d_in[11];
  const void* bh = d_in[12];
  const void* Wphi = d_in[13];
  const void* bphi = d_in[14];
  const void* Wo = d_in[15];
  const void* bo = d_in[16];

  const int n_q = in_sizes[0];   // B*S*1024
  const int Srows = n_q >> 10;   // B*S
  const int S = Srows >> 1;      // B = 2

  char* ws = (char*)d_ws;
  const size_t MB = 1024 * 1024;

  int* mode = (int*)(ws);
  __bf16* sv = (__bf16*)(ws + 4096);
  __bf16* bz_c   = sv + 0 * 4096;
  __bf16* lng_c  = sv + 1 * 4096;
  __bf16* lnb_c  = sv + 2 * 4096;
  __bf16* bo_c   = sv + 3 * 4096;
  __bf16* bphi_c = sv + 4 * 4096;
  __bf16* wphi_c = sv + 5 * 4096;   // 4096 elems
  __bf16* bqrh   = sv + 6 * 4096;   // 3072 elems
  __bf16* WzT    = (__bf16*)(ws + 1 * MB);   // 2 MB
  __bf16* WoT    = (__bf16*)(ws + 3 * MB);   // 2 MB
  __bf16* WqrhT  = (__bf16*)(ws + 5 * MB);   // 6 MB
  float*  Zraw   = (float*) (ws + 11 * MB);  // 16 MB, dead after ln
  __bf16* Z      = (__bf16*)(ws + 27 * MB);  // 8 MB, dead after qrh gemm
  __bf16* Qf     = (__bf16*)(ws + 35 * MB);  // 8 MB, dead after phasor Q
  __bf16* Rf     = (__bf16*)(ws + 43 * MB);  // 8 MB, dead after phasor R
  __bf16* Hv     = (__bf16*)(ws + 51 * MB);  // 8 MB, dead after hvt
  __bf16* Rc     = (__bf16*)(ws + 59 * MB);  // 16 MB (top = 75 MB, proven safe)
  __bf16* Qc     = (__bf16*)(ws + 11 * MB);  // 16 MB over dead Zraw
  __bf16* HvT    = (__bf16*)(ws + 27 * MB);  // 8 MB over dead Z
  __bf16* Aout   = (__bf16*)(ws + 35 * MB);  // 8 MB over dead Qf

  dim3 blk(256);
  detect_k<<<1, 64, 0, stream>>>((const unsigned short*)query, mode);

  CvtJobs cj;
  cj.src[0] = bz;   cj.dst[0] = bz_c;
  cj.src[1] = ln_g; cj.dst[1] = lng_c;
  cj.src[2] = ln_b; cj.dst[2] = lnb_c;
  cj.src[3] = bo;   cj.dst[3] = bo_c;
  cj.src[4] = bphi; cj.dst[4] = bphi_c;
  cj.src[5] = Wphi; cj.dst[5] = wphi_c;
  cj.src[6] = bq;   cj.dst[6] = bqrh;
  cj.src[7] = br;   cj.dst[7] = bqrh + 1024;
  cj.src[8] = bh;   cj.dst[8] = bqrh + 2048;
  cvt_all_k<<<12, blk, 0, stream>>>(cj, mode);

  TJobs tj;
  tj.src[0] = Wz; tj.dst[0] = WzT;
  tj.src[1] = Wo; tj.dst[1] = WoT;
  tj.src[2] = Wq; tj.dst[2] = WqrhT;
  tj.src[3] = Wr; tj.dst[3] = WqrhT + 1024 * 1024;
  tj.src[4] = Wh; tj.dst[4] = WqrhT + 2 * 1024 * 1024;
  tcvt_all_k<<<dim3(16, 16, 5), blk, 0, stream>>>(tj, mode);

  dim3 ggrid(8, Srows / 64);
  gemm64m_k<true, true><<<ggrid, blk, 0, stream>>>(query, WzT, bz_c, (void*)Zraw,
                                                   Srows, 1024, 1024, mode);
  ln_k<<<Srows, blk, 0, stream>>>(Zraw, lng_c, lnb_c, Z);
  qrh64_k<<<dim3(24, Srows / 64), blk, 0, stream>>>(Z, WqrhT, bqrh, Qf, Rf, Hv, Srows);
  phasor_mfma_k<<<dim3((Srows * 16) / 128, 2), blk, 0, stream>>>(Qf, Rf, wphi_c, bphi_c, Qc, Rc);
  hvt_k<<<dim3(S / 64, 16, 2), blk, 0, stream>>>(Hv, HvT, S);
  attn_k<<<dim3((S / 64) * 32), blk, 0, stream>>>(Qc, Rc, HvT, Aout, S);
  gemm64m_k<true, false><<<ggrid, blk, 0, stream>>>(Aout, WoT, bo_c, d_out,
                                                    Srows, 1024, 1024, mode);
}

// Round 5
// 370.966 us; speedup vs baseline: 1.6256x; 1.1925x over previous
//
#include <hip/hip_runtime.h>

#define DEV __device__ __forceinline__

typedef __bf16 bf16x8 __attribute__((ext_vector_type(8)));
typedef float f32x4 __attribute__((ext_vector_type(4)));

DEV float b2f(__bf16 v) { return (float)v; }
DEV __bf16 f2b(float v) { return (__bf16)v; }

DEV void gload16(const __bf16* g, __bf16* l) {
  __builtin_amdgcn_global_load_lds((const __attribute__((address_space(1))) unsigned*)g,
                                   (__attribute__((address_space(3))) unsigned*)l, 16, 0, 0);
}

// ---------------------------------------------------------------- dtype detect (3-way)
__global__ void detect_k(const unsigned short* __restrict__ q, int* __restrict__ mode) {
  const int lane = threadIdx.x & 63;
  int cntNaN = 0, cntSmall = 0;
  for (int i = lane; i < 16384; i += 64) {
    const unsigned ef = (q[i] >> 7) & 0xFF;
    if (ef == 0xFF) cntNaN++;
    if (ef < 0x70) cntSmall++;
  }
#pragma unroll
  for (int o = 32; o > 0; o >>= 1) {
    cntNaN += __shfl_down(cntNaN, o);
    cntSmall += __shfl_down(cntSmall, o);
  }
  if (lane == 0) *mode = (cntNaN >= 4) ? 1 : ((cntSmall > 2000) ? 2 : 0);
}

// ---------------------------------------------------------------- query -> bf16 (once; GEMMs then pure-bf16)
__global__ __launch_bounds__(256) void qcvt_k(const void* __restrict__ src,
                                              __bf16* __restrict__ dst,
                                              int n8, const int* __restrict__ mode) {
  const int i = blockIdx.x * 256 + threadIdx.x;
  if (i >= n8) return;
  const int m = *mode;
  union { __bf16 h[8]; int4 u; } pk;
  if (m == 1) {
    const float4* p = (const float4*)src + (size_t)i * 2;
    const float4 a = p[0], b = p[1];
    pk.h[0] = f2b(a.x); pk.h[1] = f2b(a.y); pk.h[2] = f2b(a.z); pk.h[3] = f2b(a.w);
    pk.h[4] = f2b(b.x); pk.h[5] = f2b(b.y); pk.h[6] = f2b(b.z); pk.h[7] = f2b(b.w);
  } else if (m == 2) {
    const _Float16* p = (const _Float16*)src + (size_t)i * 8;
#pragma unroll
    for (int t = 0; t < 8; t++) pk.h[t] = f2b((float)p[t]);
  } else {
    pk.u = ((const int4*)src)[i];
  }
  ((int4*)dst)[i] = pk.u;
}

// ---------------------------------------------------------------- fused small-vector convert
struct CvtJobs {
  const void* src[9];
  __bf16* dst[9];
};
__global__ __launch_bounds__(256) void cvt_all_k(CvtJobs J, const int* __restrict__ mode) {
  const int bb = blockIdx.x;
  int job, off;
  if (bb < 4) { job = bb; off = 0; }
  else if (bb == 4) { job = 4; off = 0; }
  else if (bb < 9) { job = 5; off = (bb - 5) * 1024; }
  else { job = 6 + (bb - 9); off = 0; }
  const int n = (job == 4) ? 64 : (job == 5) ? 4096 : 1024;
  const int m = *mode;
  const void* s = J.src[job];
  __bf16* d = J.dst[job];
  const int rem = n - off;
  const int cnt = rem > 1024 ? 1024 : rem;
  for (int i = threadIdx.x; i < cnt; i += 256) {
    const int idx = off + i;
    const float v = (m == 1) ? ((const float*)s)[idx]
                  : (m == 2) ? (float)((const _Float16*)s)[idx]
                             : b2f(((const __bf16*)s)[idx]);
    d[idx] = f2b(v);
  }
}

// ---------------------------------------------------------------- fused LDS-tiled transpose+convert
struct TJobs {
  const void* src[5];
  __bf16* dst[5];
};
__global__ __launch_bounds__(256) void tcvt_all_k(TJobs J, const int* __restrict__ mode) {
  __shared__ __bf16 tile[64][68];
  const void* in = J.src[blockIdx.z];
  __bf16* out = J.dst[blockIdx.z];
  const int c0 = blockIdx.x * 64, r0 = blockIdx.y * 64;
  const int tid = threadIdx.x;
  const int m = *mode;
  for (int i = tid; i < 64 * 16; i += 256) {
    int r = i >> 4, cc = (i & 15) * 4;
    const size_t base = (size_t)(r0 + r) * 1024 + c0 + cc;
    if (m == 1) {
      float4 v = *(const float4*)((const float*)in + base);
      tile[r][cc + 0] = f2b(v.x);
      tile[r][cc + 1] = f2b(v.y);
      tile[r][cc + 2] = f2b(v.z);
      tile[r][cc + 3] = f2b(v.w);
    } else if (m == 2) {
      const _Float16* p = (const _Float16*)in + base;
      tile[r][cc + 0] = f2b((float)p[0]);
      tile[r][cc + 1] = f2b((float)p[1]);
      tile[r][cc + 2] = f2b((float)p[2]);
      tile[r][cc + 3] = f2b((float)p[3]);
    } else {
      *(uint2*)&tile[r][cc] = *(const uint2*)((const __bf16*)in + base);
    }
  }
  __syncthreads();
  for (int i = tid; i < 64 * 16; i += 256) {
    int c = i >> 4, rr = (i & 15) * 4;
    union { __bf16 h[4]; uint2 u; } pk;
    pk.h[0] = tile[rr + 0][c];
    pk.h[1] = tile[rr + 1][c];
    pk.h[2] = tile[rr + 2][c];
    pk.h[3] = tile[rr + 3][c];
    *(uint2*)&out[(size_t)(c0 + c) * 1024 + r0 + rr] = pk.u;
  }
}

// ---------------------------------------------------------------- 2-phase GEMM, BM=BN=64
// C[M][N] = A[M][K] @ BT[N][K]^T + bias[N]. A,BT bf16. Double-buffered
// global_load_lds staging (both-sides 16B-chunk XOR swizzle), 1 barrier/K-step,
// loads in flight across MFMA phase. 1D grid, XCD-chunked swizzle, n-major.
template <bool OUT_F32>
__global__ __launch_bounds__(256) void gemm2p_k(const __bf16* __restrict__ A,
                                                const __bf16* __restrict__ BT,
                                                const __bf16* __restrict__ bias,
                                                void* __restrict__ Cout,
                                                int M, int N, int K) {
  __shared__ __bf16 As[2][64 * 64];
  __shared__ __bf16 Bs[2][64 * 64];
  const int tid = threadIdx.x, lane = tid & 63, wv = tid >> 6;
  const int quad = lane >> 4, l16 = lane & 15;
  const int nblk = gridDim.x, chunk = nblk >> 3;
  const int hb = blockIdx.x;
  const int lb = (hb & 7) * chunk + (hb >> 3);
  const int mcnt = M >> 6;
  const int ni = lb / mcnt, mi = lb - ni * mcnt;
  const int m0 = mi * 64, n0 = ni * 64;
  const int wm = (wv >> 1) * 32, wn = (wv & 1) * 32;

  // staging source offsets (pre-swizzled): chunk ci -> row=ci>>3, cc=ci&7
  int s_src[2];
#pragma unroll
  for (int u = 0; u < 2; u++) {
    const int ci = tid + u * 256;
    const int r = ci >> 3, cc = ci & 7;
    s_src[u] = r * K + ((cc ^ (r & 7)) * 8);
  }

#define GSTAGE(BUF, K0)                                                   \
  {                                                                       \
    const __bf16* a_ = A + (size_t)m0 * K + (K0);                         \
    const __bf16* b_ = BT + (size_t)n0 * K + (K0);                        \
    gload16(a_ + s_src[0], &As[BUF][tid * 8]);                            \
    gload16(a_ + s_src[1], &As[BUF][(tid + 256) * 8]);                    \
    gload16(b_ + s_src[0], &Bs[BUF][tid * 8]);                            \
    gload16(b_ + s_src[1], &Bs[BUF][(tid + 256) * 8]);                    \
  }

  f32x4 acc[2][2] = {};
  const int nk = K >> 6;
  const int key = l16 & 7;

  GSTAGE(0, 0);
  __syncthreads();

  for (int t = 0; t < nk; ++t) {
    const int cur = t & 1;
    if (t + 1 < nk) GSTAGE(cur ^ 1, (t + 1) * 64);
#pragma unroll
    for (int s = 0; s < 2; s++) {
      const int co = ((4 * s + quad) ^ key) * 8;
      bf16x8 af[2], bfr[2];
#pragma unroll
      for (int i = 0; i < 2; i++) af[i] = *(const bf16x8*)&As[cur][(wm + i * 16 + l16) * 64 + co];
#pragma unroll
      for (int j = 0; j < 2; j++) bfr[j] = *(const bf16x8*)&Bs[cur][(wn + j * 16 + l16) * 64 + co];
#pragma unroll
      for (int i = 0; i < 2; i++)
#pragma unroll
        for (int j = 0; j < 2; j++)
          acc[i][j] = __builtin_amdgcn_mfma_f32_16x16x32_bf16(af[i], bfr[j], acc[i][j], 0, 0, 0);
    }
    __syncthreads();
  }
#undef GSTAGE

#pragma unroll
  for (int j = 0; j < 2; j++) {
    const int col = n0 + wn + j * 16 + l16;
    const float bv = b2f(bias[col]);
#pragma unroll
    for (int i = 0; i < 2; i++) {
#pragma unroll
      for (int r = 0; r < 4; r++) {
        const int row = m0 + wm + i * 16 + quad * 4 + r;
        const float v = acc[i][j][r] + bv;
        if (OUT_F32)
          ((float*)Cout)[(size_t)row * N + col] = v;
        else
          ((__bf16*)Cout)[(size_t)row * N + col] = f2b(v);
      }
    }
  }
}

// ---------------------------------------------------------------- 2-phase fused Q/R/H GEMM (BM=BN=64)
__global__ __launch_bounds__(256) void qrh2p_k(const __bf16* __restrict__ A,
                                               const __bf16* __restrict__ BT3,
                                               const __bf16* __restrict__ bias3,
                                               __bf16* __restrict__ Qf,
                                               __bf16* __restrict__ Rf,
                                               __bf16* __restrict__ Hv,
                                               int M) {
  __shared__ __bf16 As[2][64 * 64];
  __shared__ __bf16 Bs[2][64 * 64];
  const int tid = threadIdx.x, lane = tid & 63, wv = tid >> 6;
  const int quad = lane >> 4, l16 = lane & 15;
  const int nblk = gridDim.x, chunk = nblk >> 3;
  const int hb = blockIdx.x;
  const int lb = (hb & 7) * chunk + (hb >> 3);
  const int mcnt = M >> 6;
  const int ni = lb / mcnt, mi = lb - ni * mcnt;
  const int m0 = mi * 64, n0g = ni * 64;
  const int which = n0g >> 10, n0 = n0g & 1023;
  __bf16* out = (which == 0) ? Qf : (which == 1) ? Rf : Hv;
  const int wm = (wv >> 1) * 32, wn = (wv & 1) * 32;
  const int K = 1024;

  int s_src[2];
#pragma unroll
  for (int u = 0; u < 2; u++) {
    const int ci = tid + u * 256;
    const int r = ci >> 3, cc = ci & 7;
    s_src[u] = r * K + ((cc ^ (r & 7)) * 8);
  }

#define GSTAGE(BUF, K0)                                                   \
  {                                                                       \
    const __bf16* a_ = A + (size_t)m0 * K + (K0);                         \
    const __bf16* b_ = BT3 + (size_t)n0g * K + (K0);                      \
    gload16(a_ + s_src[0], &As[BUF][tid * 8]);                            \
    gload16(a_ + s_src[1], &As[BUF][(tid + 256) * 8]);                    \
    gload16(b_ + s_src[0], &Bs[BUF][tid * 8]);                            \
    gload16(b_ + s_src[1], &Bs[BUF][(tid + 256) * 8]);                    \
  }

  f32x4 acc[2][2] = {};
  const int key = l16 & 7;

  GSTAGE(0, 0);
  __syncthreads();

  for (int t = 0; t < 16; ++t) {
    const int cur = t & 1;
    if (t + 1 < 16) GSTAGE(cur ^ 1, (t + 1) * 64);
#pragma unroll
    for (int s = 0; s < 2; s++) {
      const int co = ((4 * s + quad) ^ key) * 8;
      bf16x8 af[2], bfr[2];
#pragma unroll
      for (int i = 0; i < 2; i++) af[i] = *(const bf16x8*)&As[cur][(wm + i * 16 + l16) * 64 + co];
#pragma unroll
      for (int j = 0; j < 2; j++) bfr[j] = *(const bf16x8*)&Bs[cur][(wn + j * 16 + l16) * 64 + co];
#pragma unroll
      for (int i = 0; i < 2; i++)
#pragma unroll
        for (int j = 0; j < 2; j++)
          acc[i][j] = __builtin_amdgcn_mfma_f32_16x16x32_bf16(af[i], bfr[j], acc[i][j], 0, 0, 0);
    }
    __syncthreads();
  }
#undef GSTAGE

#pragma unroll
  for (int j = 0; j < 2; j++) {
    const int colg = n0g + wn + j * 16 + l16;
    const int col = n0 + wn + j * 16 + l16;
    const float bv = b2f(bias3[colg]);
#pragma unroll
    for (int i = 0; i < 2; i++) {
#pragma unroll
      for (int r = 0; r < 4; r++) {
        const int row = m0 + wm + i * 16 + quad * 4 + r;
        out[(size_t)row * 1024 + col] = f2b(acc[i][j][r] + bv);
      }
    }
  }
}

// ---------------------------------------------------------------- LayerNorm (cleared)
__global__ __launch_bounds__(256) void ln_k(const float* __restrict__ Zraw,
                                            const __bf16* __restrict__ g,
                                            const __bf16* __restrict__ bb,
                                            __bf16* __restrict__ Z) {
  __shared__ float red[8];
  const int row = blockIdx.x, tid = threadIdx.x, lane = tid & 63, wv = tid >> 6;
  const float* x = Zraw + (size_t)row * 1024;
  float4 v = *(const float4*)&x[tid * 4];
  float s = v.x + v.y + v.z + v.w;
  float ss = v.x * v.x + v.y * v.y + v.z * v.z + v.w * v.w;
#pragma unroll
  for (int o = 32; o > 0; o >>= 1) {
    s += __shfl_down(s, o);
    ss += __shfl_down(ss, o);
  }
  if (lane == 0) { red[wv] = s; red[4 + wv] = ss; }
  __syncthreads();
  const float S = red[0] + red[1] + red[2] + red[3];
  const float SS = red[4] + red[5] + red[6] + red[7];
  const float mu = S * (1.f / 1024.f);
  const float var = SS * (1.f / 1024.f) - mu * mu;
  const float rstd = rsqrtf(var + 1e-5f);
  const int c = tid * 4;
  float xs[4] = {v.x, v.y, v.z, v.w};
  union { __bf16 h[4]; uint2 u; } pk;
#pragma unroll
  for (int i = 0; i < 4; i++)
    pk.h[i] = f2b((xs[i] - mu) * rstd * b2f(g[c + i]) + b2f(bb[c + i]));
  *(uint2*)&Z[(size_t)row * 1024 + c] = pk.u;
}

// ---------------------------------------------------------------- MFMA phasor (cleared r2)
__global__ __launch_bounds__(256) void phasor_mfma_k(const __bf16* __restrict__ Qf,
                                                     const __bf16* __restrict__ Rf,
                                                     const __bf16* __restrict__ Wphi,
                                                     const __bf16* __restrict__ bphi,
                                                     __bf16* __restrict__ Qc,
                                                     __bf16* __restrict__ Rc) {
  __shared__ __bf16 Qs[128][76];
  __shared__ __bf16 WT[64][76];
  const __bf16* in = blockIdx.y ? Rf : Qf;
  __bf16* out = blockIdx.y ? Rc : Qc;
  const int tid = threadIdx.x, lane = tid & 63, wv = tid >> 6;
  const int quad = lane >> 4, l16 = lane & 15;
  const size_t m0 = (size_t)blockIdx.x * 128;
  for (int i = tid; i < 1024; i += 256) {
    int r = i >> 3, c = (i & 7) * 8;
    *(int4*)&Qs[r][c] = *(const int4*)&in[(m0 + r) * 64 + c];
  }
  for (int i = tid; i < 4096; i += 256) WT[i & 63][i >> 6] = Wphi[i];
  __syncthreads();
  f32x4 acc[2][4] = {};
#pragma unroll
  for (int s = 0; s < 2; s++) {
    const int ka = s * 32 + quad * 8;
    bf16x8 bfr[4];
#pragma unroll
    for (int j = 0; j < 4; j++) bfr[j] = *(const bf16x8*)&WT[j * 16 + l16][ka];
#pragma unroll
    for (int i = 0; i < 2; i++) {
      const bf16x8 af = *(const bf16x8*)&Qs[wv * 32 + i * 16 + l16][ka];
#pragma unroll
      for (int j = 0; j < 4; j++)
        acc[i][j] = __builtin_amdgcn_mfma_f32_16x16x32_bf16(af, bfr[j], acc[i][j], 0, 0, 0);
    }
  }
#pragma unroll
  for (int i = 0; i < 2; i++)
#pragma unroll
    for (int j = 0; j < 4; j++) {
      const int col = j * 16 + l16;
      const float bj = b2f(bphi[col]);
#pragma unroll
      for (int r = 0; r < 4; r++) {
        const int row = wv * 32 + i * 16 + quad * 4 + r;
        const float phi = acc[i][j][r] + bj;
        float sn, cs;
        __sincosf(phi, &sn, &cs);
        const float qv = b2f(Qs[row][col]);
        const size_t ob = (m0 + row) * 128;
        out[ob + col] = f2b(qv * cs);
        out[ob + 64 + col] = f2b(qv * sn);
      }
    }
}

// ---------------------------------------------------------------- Hv transpose (cleared)
__global__ __launch_bounds__(256) void hvt_k(const __bf16* __restrict__ Hv,
                                             __bf16* __restrict__ HvT, int S) {
  __shared__ __bf16 t[64][72];
  const int tt = blockIdx.x * 64, h = blockIdx.y, b = blockIdx.z;
  const int tid = threadIdx.x;
  for (int i = tid; i < 512; i += 256) {
    int tok = i >> 3, dc = (i & 7) * 8;
    *(int4*)&t[tok][dc] = *(const int4*)&Hv[((size_t)(b * S + tt + tok) * 16 + h) * 64 + dc];
  }
  __syncthreads();
  for (int i = tid; i < 1024; i += 256) {
    int d = i >> 4, tc = (i & 15) * 4;
    union { __bf16 h4[4]; uint2 u; } pk;
    pk.h4[0] = t[tc + 0][d];
    pk.h4[1] = t[tc + 1][d];
    pk.h4[2] = t[tc + 2][d];
    pk.h4[3] = t[tc + 3][d];
    *(uint2*)&HvT[(((size_t)(b * 16 + h) * 64 + d) * S) + tt + tc] = pk.u;
  }
}

// ---------------------------------------------------------------- flash attention v5 (+setprio)
__global__ __launch_bounds__(256) void attn_k(const __bf16* __restrict__ Qc,
                                              const __bf16* __restrict__ Rc,
                                              const __bf16* __restrict__ HvT,
                                              __bf16* __restrict__ Aout, int S) {
  __shared__ __bf16 Rs[2][64 * 128];  // 32768 B, linear
  __shared__ __bf16 Hs[2][64 * 64];   // 16384 B, linear -> total 49152 B
  const int tid = threadIdx.x, lane = tid & 63, wv = tid >> 6;
  const int quad = lane >> 4, l16 = lane & 15;
  const int nblk = gridDim.x;
  const int chunk = nblk >> 3;
  const int hb = blockIdx.x;
  const int lb = (hb & 7) * chunk + (hb >> 3);
  const int nx = nblk >> 5;     // = S/64
  const int x = lb % nx;
  const int rest = lb / nx;
  const int h = rest & 15, b = rest >> 4;
  const int q0 = x * 64;

  bf16x8 qf[4];
  {
    const __bf16* qp = Qc + ((size_t)(b * S + q0 + wv * 16 + l16) * 16 + h) * 128 + quad * 8;
#pragma unroll
    for (int s = 0; s < 4; s++) qf[s] = *(const bf16x8*)(qp + s * 32);
  }

  const size_t rcb = ((size_t)b * S * 16 + h) * 128;
  const size_t hvb = (size_t)(b * 16 + h) * 64 * S;

  int rs_src[4], hs_src[2];
#pragma unroll
  for (int u = 0; u < 4; u++) {
    const int r = 4 * (wv * 4 + u) + (lane >> 4);
    rs_src[u] = r * 2048 + (((lane & 15) ^ (r & 7)) * 8);
  }
#pragma unroll
  for (int u = 0; u < 2; u++) {
    const int row = 8 * (wv * 2 + u) + (lane >> 3);
    hs_src[u] = row * S + (((lane & 7) ^ (row & 7)) * 8);
  }

#define STAGE(BUF, TILE)                                                        \
  {                                                                             \
    const __bf16* rc_ = Rc + rcb + (size_t)(TILE) * 64 * 2048;                  \
    const __bf16* hv_ = HvT + hvb + (TILE) * 64;                                \
    _Pragma("unroll")                                                           \
    for (int u = 0; u < 4; u++)                                                 \
      gload16(rc_ + rs_src[u], &Rs[BUF][(wv * 4 + u) * 512]);                   \
    _Pragma("unroll")                                                           \
    for (int u = 0; u < 2; u++)                                                 \
      gload16(hv_ + hs_src[u], &Hs[BUF][(wv * 2 + u) * 512]);                   \
  }

  f32x4 oacc[4] = {};
  float rssq = 0.f;
  const int nt = S >> 6;

  STAGE(0, 0);
  __syncthreads();

  const int srcA = ((quad & 1) << 1) | (quad >> 1);
  const int adA = ((srcA << 4) | l16) << 2;
  const int adB = (((srcA ^ 1) << 4) | l16) << 2;
  const bool par = (quad & 1) != 0;
  const bool hi = (quad >> 1) != 0;
  const int key = l16 & 7;

  for (int it = 0; it < nt; ++it) {
    const int cur = it & 1;
    if (it + 1 < nt) STAGE(cur ^ 1, it + 1);

    f32x4 sacc[4] = {};
    __builtin_amdgcn_s_setprio(1);
#pragma unroll
    for (int s = 0; s < 4; s++) {
      const int co = ((4 * s + quad) ^ key) * 8;
#pragma unroll
      for (int jt = 0; jt < 4; jt++) {
        const bf16x8 rf = *(const bf16x8*)&Rs[cur][(jt * 16 + l16) * 128 + co];
        sacc[jt] = __builtin_amdgcn_mfma_f32_16x16x32_bf16(rf, qf[s], sacc[jt], 0, 0, 0);
      }
    }
    __builtin_amdgcn_s_setprio(0);

    unsigned pk[4][2];
#pragma unroll
    for (int jt = 0; jt < 4; jt++) {
      rssq += sacc[jt][0] * sacc[jt][0] + sacc[jt][1] * sacc[jt][1] +
              sacc[jt][2] * sacc[jt][2] + sacc[jt][3] * sacc[jt][3];
      union { __bf16 h2[2]; unsigned u; } p0, p1;
      p0.h2[0] = f2b(sacc[jt][0]); p0.h2[1] = f2b(sacc[jt][1]);
      p1.h2[0] = f2b(sacc[jt][2]); p1.h2[1] = f2b(sacc[jt][3]);
      pk[jt][0] = p0.u; pk[jt][1] = p1.u;
    }

#pragma unroll
    for (int s2 = 0; s2 < 2; s2++) {
      bf16x8 hf[4];
      const int co2 = ((4 * s2 + quad) ^ key) * 8;
#pragma unroll
      for (int jd = 0; jd < 4; jd++)
        hf[jd] = *(const bf16x8*)&Hs[cur][(jd * 16 + l16) * 64 + co2];
      const int jA = 2 * s2, jB = 2 * s2 + 1;
      const unsigned o0 = par ? pk[jB][0] : pk[jA][0];
      const unsigned o1 = par ? pk[jB][1] : pk[jA][1];
      const unsigned o2 = par ? pk[jA][0] : pk[jB][0];
      const unsigned o3 = par ? pk[jA][1] : pk[jB][1];
      const unsigned r0 = (unsigned)__builtin_amdgcn_ds_bpermute(adA, (int)o0);
      const unsigned r1 = (unsigned)__builtin_amdgcn_ds_bpermute(adA, (int)o1);
      const unsigned r2 = (unsigned)__builtin_amdgcn_ds_bpermute(adB, (int)o2);
      const unsigned r3 = (unsigned)__builtin_amdgcn_ds_bpermute(adB, (int)o3);
      union { unsigned u[4]; bf16x8 v; } bw;
      bw.u[0] = hi ? r2 : r0;
      bw.u[1] = hi ? r3 : r1;
      bw.u[2] = hi ? r0 : r2;
      bw.u[3] = hi ? r1 : r3;
      __builtin_amdgcn_s_setprio(1);
#pragma unroll
      for (int jd = 0; jd < 4; jd++)
        oacc[jd] = __builtin_amdgcn_mfma_f32_16x16x32_bf16(hf[jd], bw.v, oacc[jd], 0, 0, 0);
      __builtin_amdgcn_s_setprio(0);
    }
    __syncthreads();
  }
#undef STAGE

  {
    float t = rssq;
    t += __shfl_xor(t, 16);
    t += __shfl_xor(t, 32);
    const float inv = 1.0f / fmaxf(sqrtf(t), 1e-12f);
    const size_t orow = (size_t)(b * S + q0 + wv * 16 + l16) * 1024 + h * 64;
#pragma unroll
    for (int jd = 0; jd < 4; jd++) {
      union { __bf16 h4[4]; uint2 u2; } o;
#pragma unroll
      for (int r = 0; r < 4; r++) o.h4[r] = f2b(oacc[jd][r] * inv);
      *(uint2*)&Aout[orow + jd * 16 + quad * 4] = o.u2;
    }
  }
}

// ---------------------------------------------------------------- launch
extern "C" void kernel_launch(void* const* d_in, const int* in_sizes, int n_in,
                              void* d_out, int out_size, void* d_ws, size_t ws_size,
                              hipStream_t stream) {
  const void* query = d_in[0];
  const void* Wz = d_in[3];
  const void* bz = d_in[4];
  const void* ln_g = d_in[5];
  const void* ln_b = d_in[6];
  const void* Wq = d_in[7];
  const void* bq = d_in[8];
  const void* Wr = d_in[9];
  const void* br = d_in[10];
  const void* Wh = d_in[11];
  const void* bh = d_in[12];
  const void* Wphi = d_in[13];
  const void* bphi = d_in[14];
  const void* Wo = d_in[15];
  const void* bo = d_in[16];

  const int n_q = in_sizes[0];   // B*S*1024
  const int Srows = n_q >> 10;   // B*S
  const int S = Srows >> 1;      // B = 2

  char* ws = (char*)d_ws;
  const size_t MB = 1024 * 1024;

  int* mode = (int*)(ws);
  __bf16* sv = (__bf16*)(ws + 4096);
  __bf16* bz_c   = sv + 0 * 4096;
  __bf16* lng_c  = sv + 1 * 4096;
  __bf16* lnb_c  = sv + 2 * 4096;
  __bf16* bo_c   = sv + 3 * 4096;
  __bf16* bphi_c = sv + 4 * 4096;
  __bf16* wphi_c = sv + 5 * 4096;   // 4096 elems
  __bf16* bqrh   = sv + 6 * 4096;   // 3072 elems
  __bf16* WzT    = (__bf16*)(ws + 1 * MB);   // 2 MB
  __bf16* WoT    = (__bf16*)(ws + 3 * MB);   // 2 MB
  __bf16* WqrhT  = (__bf16*)(ws + 5 * MB);   // 6 MB
  float*  Zraw   = (float*) (ws + 11 * MB);  // 16 MB, dead after ln
  __bf16* Z      = (__bf16*)(ws + 27 * MB);  // 8 MB, dead after qrh gemm
  __bf16* Qf     = (__bf16*)(ws + 35 * MB);  // 8 MB, dead after phasor Q
  __bf16* Rf     = (__bf16*)(ws + 43 * MB);  // 8 MB, dead after phasor R
  __bf16* Hv     = (__bf16*)(ws + 51 * MB);  // 8 MB, dead after hvt
  __bf16* Qbf    = (__bf16*)(ws + 59 * MB);  // 8 MB, dead after z-gemm (before Rc is written)
  __bf16* Rc     = (__bf16*)(ws + 59 * MB);  // 16 MB (top = 75 MB, proven safe)
  __bf16* Qc     = (__bf16*)(ws + 11 * MB);  // 16 MB over dead Zraw
  __bf16* HvT    = (__bf16*)(ws + 27 * MB);  // 8 MB over dead Z
  __bf16* Aout   = (__bf16*)(ws + 35 * MB);  // 8 MB over dead Qf

  dim3 blk(256);
  detect_k<<<1, 64, 0, stream>>>((const unsigned short*)query, mode);

  CvtJobs cj;
  cj.src[0] = bz;   cj.dst[0] = bz_c;
  cj.src[1] = ln_g; cj.dst[1] = lng_c;
  cj.src[2] = ln_b; cj.dst[2] = lnb_c;
  cj.src[3] = bo;   cj.dst[3] = bo_c;
  cj.src[4] = bphi; cj.dst[4] = bphi_c;
  cj.src[5] = Wphi; cj.dst[5] = wphi_c;
  cj.src[6] = bq;   cj.dst[6] = bqrh;
  cj.src[7] = br;   cj.dst[7] = bqrh + 1024;
  cj.src[8] = bh;   cj.dst[8] = bqrh + 2048;
  cvt_all_k<<<12, blk, 0, stream>>>(cj, mode);

  TJobs tj;
  tj.src[0] = Wz; tj.dst[0] = WzT;
  tj.src[1] = Wo; tj.dst[1] = WoT;
  tj.src[2] = Wq; tj.dst[2] = WqrhT;
  tj.src[3] = Wr; tj.dst[3] = WqrhT + 1024 * 1024;
  tj.src[4] = Wh; tj.dst[4] = WqrhT + 2 * 1024 * 1024;
  tcvt_all_k<<<dim3(16, 16, 5), blk, 0, stream>>>(tj, mode);

  qcvt_k<<<(Srows * 1024 / 8 + 255) / 256, blk, 0, stream>>>(query, Qbf, Srows * 128, mode);

  const int mcnt = Srows / 64;
  gemm2p_k<true><<<16 * mcnt, blk, 0, stream>>>(Qbf, WzT, bz_c, (void*)Zraw,
                                                Srows, 1024, 1024);
  ln_k<<<Srows, blk, 0, stream>>>(Zraw, lng_c, lnb_c, Z);
  qrh2p_k<<<48 * mcnt, blk, 0, stream>>>(Z, WqrhT, bqrh, Qf, Rf, Hv, Srows);
  phasor_mfma_k<<<dim3((Srows * 16) / 128, 2), blk, 0, stream>>>(Qf, Rf, wphi_c, bphi_c, Qc, Rc);
  hvt_k<<<dim3(S / 64, 16, 2), blk, 0, stream>>>(Hv, HvT, S);
  attn_k<<<dim3((S / 64) * 32), blk, 0, stream>>>(Qc, Rc, HvT, Aout, S);
  gemm2p_k<true><<<16 * mcnt, blk, 0, stream>>>(Aout, WoT, bo_c, d_out,
                                                Srows, 1024, 1024);
}

// Round 6
// 311.429 us; speedup vs baseline: 1.9363x; 1.1912x over previous
//
#include <hip/hip_runtime.h>

#define DEV __device__ __forceinline__

typedef __bf16 bf16x8 __attribute__((ext_vector_type(8)));
typedef float f32x4 __attribute__((ext_vector_type(4)));

DEV float b2f(__bf16 v) { return (float)v; }
DEV __bf16 f2b(float v) { return (__bf16)v; }

DEV void gload16(const __bf16* g, __bf16* l) {
  __builtin_amdgcn_global_load_lds((const __attribute__((address_space(1))) unsigned*)g,
                                   (__attribute__((address_space(3))) unsigned*)l, 16, 0, 0);
}

// ---------------------------------------------------------------- dtype detect (3-way)
__global__ void detect_k(const unsigned short* __restrict__ q, int* __restrict__ mode) {
  const int lane = threadIdx.x & 63;
  int cntNaN = 0, cntSmall = 0;
  for (int i = lane; i < 16384; i += 64) {
    const unsigned ef = (q[i] >> 7) & 0xFF;
    if (ef == 0xFF) cntNaN++;
    if (ef < 0x70) cntSmall++;
  }
#pragma unroll
  for (int o = 32; o > 0; o >>= 1) {
    cntNaN += __shfl_down(cntNaN, o);
    cntSmall += __shfl_down(cntSmall, o);
  }
  if (lane == 0) *mode = (cntNaN >= 4) ? 1 : ((cntSmall > 2000) ? 2 : 0);
}

// ---------------------------------------------------------------- query -> bf16 (once)
__global__ __launch_bounds__(256) void qcvt_k(const void* __restrict__ src,
                                              __bf16* __restrict__ dst,
                                              int n8, const int* __restrict__ mode) {
  const int i = blockIdx.x * 256 + threadIdx.x;
  if (i >= n8) return;
  const int m = *mode;
  union { __bf16 h[8]; int4 u; } pk;
  if (m == 1) {
    const float4* p = (const float4*)src + (size_t)i * 2;
    const float4 a = p[0], b = p[1];
    pk.h[0] = f2b(a.x); pk.h[1] = f2b(a.y); pk.h[2] = f2b(a.z); pk.h[3] = f2b(a.w);
    pk.h[4] = f2b(b.x); pk.h[5] = f2b(b.y); pk.h[6] = f2b(b.z); pk.h[7] = f2b(b.w);
  } else if (m == 2) {
    const _Float16* p = (const _Float16*)src + (size_t)i * 8;
#pragma unroll
    for (int t = 0; t < 8; t++) pk.h[t] = f2b((float)p[t]);
  } else {
    pk.u = ((const int4*)src)[i];
  }
  ((int4*)dst)[i] = pk.u;
}

// ---------------------------------------------------------------- fused small-vector convert
struct CvtJobs {
  const void* src[9];
  __bf16* dst[9];
};
__global__ __launch_bounds__(256) void cvt_all_k(CvtJobs J, const int* __restrict__ mode) {
  const int bb = blockIdx.x;
  int job, off;
  if (bb < 4) { job = bb; off = 0; }
  else if (bb == 4) { job = 4; off = 0; }
  else if (bb < 9) { job = 5; off = (bb - 5) * 1024; }
  else { job = 6 + (bb - 9); off = 0; }
  const int n = (job == 4) ? 64 : (job == 5) ? 4096 : 1024;
  const int m = *mode;
  const void* s = J.src[job];
  __bf16* d = J.dst[job];
  const int rem = n - off;
  const int cnt = rem > 1024 ? 1024 : rem;
  for (int i = threadIdx.x; i < cnt; i += 256) {
    const int idx = off + i;
    const float v = (m == 1) ? ((const float*)s)[idx]
                  : (m == 2) ? (float)((const _Float16*)s)[idx]
                             : b2f(((const __bf16*)s)[idx]);
    d[idx] = f2b(v);
  }
}

// ---------------------------------------------------------------- fused LDS-tiled transpose+convert
struct TJobs {
  const void* src[5];
  __bf16* dst[5];
};
__global__ __launch_bounds__(256) void tcvt_all_k(TJobs J, const int* __restrict__ mode) {
  __shared__ __bf16 tile[64][68];
  const void* in = J.src[blockIdx.z];
  __bf16* out = J.dst[blockIdx.z];
  const int c0 = blockIdx.x * 64, r0 = blockIdx.y * 64;
  const int tid = threadIdx.x;
  const int m = *mode;
  for (int i = tid; i < 64 * 16; i += 256) {
    int r = i >> 4, cc = (i & 15) * 4;
    const size_t base = (size_t)(r0 + r) * 1024 + c0 + cc;
    if (m == 1) {
      float4 v = *(const float4*)((const float*)in + base);
      tile[r][cc + 0] = f2b(v.x);
      tile[r][cc + 1] = f2b(v.y);
      tile[r][cc + 2] = f2b(v.z);
      tile[r][cc + 3] = f2b(v.w);
    } else if (m == 2) {
      const _Float16* p = (const _Float16*)in + base;
      tile[r][cc + 0] = f2b((float)p[0]);
      tile[r][cc + 1] = f2b((float)p[1]);
      tile[r][cc + 2] = f2b((float)p[2]);
      tile[r][cc + 3] = f2b((float)p[3]);
    } else {
      *(uint2*)&tile[r][cc] = *(const uint2*)((const __bf16*)in + base);
    }
  }
  __syncthreads();
  for (int i = tid; i < 64 * 16; i += 256) {
    int c = i >> 4, rr = (i & 15) * 4;
    union { __bf16 h[4]; uint2 u; } pk;
    pk.h[0] = tile[rr + 0][c];
    pk.h[1] = tile[rr + 1][c];
    pk.h[2] = tile[rr + 2][c];
    pk.h[3] = tile[rr + 3][c];
    *(uint2*)&out[(size_t)(c0 + c) * 1024 + r0 + rr] = pk.u;
  }
}

// ---------------------------------------------------------------- 2-phase GEMM, BM=BN=64 (cleared r5)
template <bool OUT_F32>
__global__ __launch_bounds__(256) void gemm2p_k(const __bf16* __restrict__ A,
                                                const __bf16* __restrict__ BT,
                                                const __bf16* __restrict__ bias,
                                                void* __restrict__ Cout,
                                                int M, int N, int K) {
  __shared__ __bf16 As[2][64 * 64];
  __shared__ __bf16 Bs[2][64 * 64];
  const int tid = threadIdx.x, lane = tid & 63, wv = tid >> 6;
  const int quad = lane >> 4, l16 = lane & 15;
  const int nblk = gridDim.x, chunk = nblk >> 3;
  const int hb = blockIdx.x;
  const int lb = (hb & 7) * chunk + (hb >> 3);
  const int mcnt = M >> 6;
  const int ni = lb / mcnt, mi = lb - ni * mcnt;
  const int m0 = mi * 64, n0 = ni * 64;
  const int wm = (wv >> 1) * 32, wn = (wv & 1) * 32;

  int s_src[2];
#pragma unroll
  for (int u = 0; u < 2; u++) {
    const int ci = tid + u * 256;
    const int r = ci >> 3, cc = ci & 7;
    s_src[u] = r * K + ((cc ^ (r & 7)) * 8);
  }

#define GSTAGE(BUF, K0)                                                   \
  {                                                                       \
    const __bf16* a_ = A + (size_t)m0 * K + (K0);                         \
    const __bf16* b_ = BT + (size_t)n0 * K + (K0);                        \
    gload16(a_ + s_src[0], &As[BUF][tid * 8]);                            \
    gload16(a_ + s_src[1], &As[BUF][(tid + 256) * 8]);                    \
    gload16(b_ + s_src[0], &Bs[BUF][tid * 8]);                            \
    gload16(b_ + s_src[1], &Bs[BUF][(tid + 256) * 8]);                    \
  }

  f32x4 acc[2][2] = {};
  const int nk = K >> 6;
  const int key = l16 & 7;

  GSTAGE(0, 0);
  __syncthreads();

  for (int t = 0; t < nk; ++t) {
    const int cur = t & 1;
    if (t + 1 < nk) GSTAGE(cur ^ 1, (t + 1) * 64);
#pragma unroll
    for (int s = 0; s < 2; s++) {
      const int co = ((4 * s + quad) ^ key) * 8;
      bf16x8 af[2], bfr[2];
#pragma unroll
      for (int i = 0; i < 2; i++) af[i] = *(const bf16x8*)&As[cur][(wm + i * 16 + l16) * 64 + co];
#pragma unroll
      for (int j = 0; j < 2; j++) bfr[j] = *(const bf16x8*)&Bs[cur][(wn + j * 16 + l16) * 64 + co];
#pragma unroll
      for (int i = 0; i < 2; i++)
#pragma unroll
        for (int j = 0; j < 2; j++)
          acc[i][j] = __builtin_amdgcn_mfma_f32_16x16x32_bf16(af[i], bfr[j], acc[i][j], 0, 0, 0);
    }
    __syncthreads();
  }
#undef GSTAGE

#pragma unroll
  for (int j = 0; j < 2; j++) {
    const int col = n0 + wn + j * 16 + l16;
    const float bv = b2f(bias[col]);
#pragma unroll
    for (int i = 0; i < 2; i++) {
#pragma unroll
      for (int r = 0; r < 4; r++) {
        const int row = m0 + wm + i * 16 + quad * 4 + r;
        const float v = acc[i][j][r] + bv;
        if (OUT_F32)
          ((float*)Cout)[(size_t)row * N + col] = v;
        else
          ((__bf16*)Cout)[(size_t)row * N + col] = f2b(v);
      }
    }
  }
}

// ---------------------------------------------------------------- 2-phase fused Q/R/H GEMM, BM=64 x BN=128
// 16 MFMA per K-step per wave (2x the 64^2 tile) against same staging latency.
__global__ __launch_bounds__(256) void qrh2p_k(const __bf16* __restrict__ A,
                                               const __bf16* __restrict__ BT3,
                                               const __bf16* __restrict__ bias3,
                                               __bf16* __restrict__ Qf,
                                               __bf16* __restrict__ Rf,
                                               __bf16* __restrict__ Hv,
                                               int M) {
  __shared__ __bf16 As[2][64 * 64];    // 16 KB
  __shared__ __bf16 Bs[2][128 * 64];   // 32 KB -> total 48 KB (3 blocks/CU)
  const int tid = threadIdx.x, lane = tid & 63, wv = tid >> 6;
  const int quad = lane >> 4, l16 = lane & 15;
  const int nblk = gridDim.x, chunk = nblk >> 3;
  const int hb = blockIdx.x;
  const int lb = (hb & 7) * chunk + (hb >> 3);
  const int mcnt = M >> 6;
  const int ni = lb / mcnt, mi = lb - ni * mcnt;
  const int m0 = mi * 64, n0g = ni * 128;
  const int which = n0g >> 10, n0 = n0g & 1023;
  __bf16* out = (which == 0) ? Qf : (which == 1) ? Rf : Hv;
  const int wm = (wv >> 1) * 32, wn = (wv & 1) * 64;
  const int K = 1024;

  int s_src[4];
#pragma unroll
  for (int u = 0; u < 4; u++) {
    const int ci = tid + u * 256;
    const int r = ci >> 3, cc = ci & 7;
    s_src[u] = r * K + ((cc ^ (r & 7)) * 8);
  }

#define GSTAGE(BUF, K0)                                                   \
  {                                                                       \
    const __bf16* a_ = A + (size_t)m0 * K + (K0);                         \
    const __bf16* b_ = BT3 + (size_t)n0g * K + (K0);                      \
    gload16(a_ + s_src[0], &As[BUF][tid * 8]);                            \
    gload16(a_ + s_src[1], &As[BUF][(tid + 256) * 8]);                    \
    _Pragma("unroll")                                                     \
    for (int u = 0; u < 4; u++)                                           \
      gload16(b_ + s_src[u], &Bs[BUF][(tid + u * 256) * 8]);              \
  }

  f32x4 acc[2][4] = {};
  const int key = l16 & 7;

  GSTAGE(0, 0);
  __syncthreads();

  for (int t = 0; t < 16; ++t) {
    const int cur = t & 1;
    if (t + 1 < 16) GSTAGE(cur ^ 1, (t + 1) * 64);
#pragma unroll
    for (int s = 0; s < 2; s++) {
      const int co = ((4 * s + quad) ^ key) * 8;
      bf16x8 af[2], bfr[4];
#pragma unroll
      for (int i = 0; i < 2; i++) af[i] = *(const bf16x8*)&As[cur][(wm + i * 16 + l16) * 64 + co];
#pragma unroll
      for (int j = 0; j < 4; j++) bfr[j] = *(const bf16x8*)&Bs[cur][(wn + j * 16 + l16) * 64 + co];
#pragma unroll
      for (int i = 0; i < 2; i++)
#pragma unroll
        for (int j = 0; j < 4; j++)
          acc[i][j] = __builtin_amdgcn_mfma_f32_16x16x32_bf16(af[i], bfr[j], acc[i][j], 0, 0, 0);
    }
    __syncthreads();
  }
#undef GSTAGE

#pragma unroll
  for (int j = 0; j < 4; j++) {
    const int colg = n0g + wn + j * 16 + l16;
    const int col = n0 + wn + j * 16 + l16;
    const float bv = b2f(bias3[colg]);
#pragma unroll
    for (int i = 0; i < 2; i++) {
#pragma unroll
      for (int r = 0; r < 4; r++) {
        const int row = m0 + wm + i * 16 + quad * 4 + r;
        out[(size_t)row * 1024 + col] = f2b(acc[i][j][r] + bv);
      }
    }
  }
}

// ---------------------------------------------------------------- LayerNorm (cleared)
__global__ __launch_bounds__(256) void ln_k(const float* __restrict__ Zraw,
                                            const __bf16* __restrict__ g,
                                            const __bf16* __restrict__ bb,
                                            __bf16* __restrict__ Z) {
  __shared__ float red[8];
  const int row = blockIdx.x, tid = threadIdx.x, lane = tid & 63, wv = tid >> 6;
  const float* x = Zraw + (size_t)row * 1024;
  float4 v = *(const float4*)&x[tid * 4];
  float s = v.x + v.y + v.z + v.w;
  float ss = v.x * v.x + v.y * v.y + v.z * v.z + v.w * v.w;
#pragma unroll
  for (int o = 32; o > 0; o >>= 1) {
    s += __shfl_down(s, o);
    ss += __shfl_down(ss, o);
  }
  if (lane == 0) { red[wv] = s; red[4 + wv] = ss; }
  __syncthreads();
  const float S = red[0] + red[1] + red[2] + red[3];
  const float SS = red[4] + red[5] + red[6] + red[7];
  const float mu = S * (1.f / 1024.f);
  const float var = SS * (1.f / 1024.f) - mu * mu;
  const float rstd = rsqrtf(var + 1e-5f);
  const int c = tid * 4;
  float xs[4] = {v.x, v.y, v.z, v.w};
  union { __bf16 h[4]; uint2 u; } pk;
#pragma unroll
  for (int i = 0; i < 4; i++)
    pk.h[i] = f2b((xs[i] - mu) * rstd * b2f(g[c + i]) + b2f(bb[c + i]));
  *(uint2*)&Z[(size_t)row * 1024 + c] = pk.u;
}

// ---------------------------------------------------------------- MFMA phasor (cleared r2)
__global__ __launch_bounds__(256) void phasor_mfma_k(const __bf16* __restrict__ Qf,
                                                     const __bf16* __restrict__ Rf,
                                                     const __bf16* __restrict__ Wphi,
                                                     const __bf16* __restrict__ bphi,
                                                     __bf16* __restrict__ Qc,
                                                     __bf16* __restrict__ Rc) {
  __shared__ __bf16 Qs[128][76];
  __shared__ __bf16 WT[64][76];
  const __bf16* in = blockIdx.y ? Rf : Qf;
  __bf16* out = blockIdx.y ? Rc : Qc;
  const int tid = threadIdx.x, lane = tid & 63, wv = tid >> 6;
  const int quad = lane >> 4, l16 = lane & 15;
  const size_t m0 = (size_t)blockIdx.x * 128;
  for (int i = tid; i < 1024; i += 256) {
    int r = i >> 3, c = (i & 7) * 8;
    *(int4*)&Qs[r][c] = *(const int4*)&in[(m0 + r) * 64 + c];
  }
  for (int i = tid; i < 4096; i += 256) WT[i & 63][i >> 6] = Wphi[i];
  __syncthreads();
  f32x4 acc[2][4] = {};
#pragma unroll
  for (int s = 0; s < 2; s++) {
    const int ka = s * 32 + quad * 8;
    bf16x8 bfr[4];
#pragma unroll
    for (int j = 0; j < 4; j++) bfr[j] = *(const bf16x8*)&WT[j * 16 + l16][ka];
#pragma unroll
    for (int i = 0; i < 2; i++) {
      const bf16x8 af = *(const bf16x8*)&Qs[wv * 32 + i * 16 + l16][ka];
#pragma unroll
      for (int j = 0; j < 4; j++)
        acc[i][j] = __builtin_amdgcn_mfma_f32_16x16x32_bf16(af, bfr[j], acc[i][j], 0, 0, 0);
    }
  }
#pragma unroll
  for (int i = 0; i < 2; i++)
#pragma unroll
    for (int j = 0; j < 4; j++) {
      const int col = j * 16 + l16;
      const float bj = b2f(bphi[col]);
#pragma unroll
      for (int r = 0; r < 4; r++) {
        const int row = wv * 32 + i * 16 + quad * 4 + r;
        const float phi = acc[i][j][r] + bj;
        float sn, cs;
        __sincosf(phi, &sn, &cs);
        const float qv = b2f(Qs[row][col]);
        const size_t ob = (m0 + row) * 128;
        out[ob + col] = f2b(qv * cs);
        out[ob + 64 + col] = f2b(qv * sn);
      }
    }
}

// ---------------------------------------------------------------- Hv transpose (cleared)
__global__ __launch_bounds__(256) void hvt_k(const __bf16* __restrict__ Hv,
                                             __bf16* __restrict__ HvT, int S) {
  __shared__ __bf16 t[64][72];
  const int tt = blockIdx.x * 64, h = blockIdx.y, b = blockIdx.z;
  const int tid = threadIdx.x;
  for (int i = tid; i < 512; i += 256) {
    int tok = i >> 3, dc = (i & 7) * 8;
    *(int4*)&t[tok][dc] = *(const int4*)&Hv[((size_t)(b * S + tt + tok) * 16 + h) * 64 + dc];
  }
  __syncthreads();
  for (int i = tid; i < 1024; i += 256) {
    int d = i >> 4, tc = (i & 15) * 4;
    union { __bf16 h4[4]; uint2 u; } pk;
    pk.h4[0] = t[tc + 0][d];
    pk.h4[1] = t[tc + 1][d];
    pk.h4[2] = t[tc + 2][d];
    pk.h4[3] = t[tc + 3][d];
    *(uint2*)&HvT[(((size_t)(b * 16 + h) * 64 + d) * S) + tt + tc] = pk.u;
  }
}

// ---------------------------------------------------------------- flash attention v6
// v6 = v3's q-tile-128 compute core (48 MFMA/wave/iter, verified r2) +
// v5's gload_lds double-buffered staging w/ both-sides XOR swizzle (verified r4).
// No setprio (r5 post-mortem: negative on lockstep schedule). grid (S/128)*32.
__global__ __launch_bounds__(256) void attn_k(const __bf16* __restrict__ Qc,
                                              const __bf16* __restrict__ Rc,
                                              const __bf16* __restrict__ HvT,
                                              __bf16* __restrict__ Aout, int S) {
  __shared__ __bf16 Rs[2][64 * 128];  // 32768 B, linear
  __shared__ __bf16 Hs[2][64 * 64];   // 16384 B, linear -> total 49152 B
  const int tid = threadIdx.x, lane = tid & 63, wv = tid >> 6;
  const int quad = lane >> 4, l16 = lane & 15;
  const int nblk = gridDim.x;   // (S/128)*32, % 8 == 0
  const int chunk = nblk >> 3;
  const int hb = blockIdx.x;
  const int lb = (hb & 7) * chunk + (hb >> 3);
  const int nx = nblk >> 5;     // = S/128
  const int x = lb % nx;
  const int rest = lb / nx;
  const int h = rest & 15, b = rest >> 4;
  const int q0 = x * 128;

  // Q fragments direct from global: wave rows q0 + wv*32 + i*16 + l16
  bf16x8 qf[2][4];
#pragma unroll
  for (int i = 0; i < 2; i++) {
    const __bf16* qp = Qc + ((size_t)(b * S + q0 + wv * 32 + i * 16 + l16) * 16 + h) * 128 + quad * 8;
#pragma unroll
    for (int s = 0; s < 4; s++) qf[i][s] = *(const bf16x8*)(qp + s * 32);
  }

  const size_t rcb = ((size_t)b * S * 16 + h) * 128;
  const size_t hvb = (size_t)(b * 16 + h) * 64 * S;

  int rs_src[4], hs_src[2];
#pragma unroll
  for (int u = 0; u < 4; u++) {
    const int r = 4 * (wv * 4 + u) + (lane >> 4);
    rs_src[u] = r * 2048 + (((lane & 15) ^ (r & 7)) * 8);
  }
#pragma unroll
  for (int u = 0; u < 2; u++) {
    const int row = 8 * (wv * 2 + u) + (lane >> 3);
    hs_src[u] = row * S + (((lane & 7) ^ (row & 7)) * 8);
  }

#define STAGE(BUF, TILE)                                                        \
  {                                                                             \
    const __bf16* rc_ = Rc + rcb + (size_t)(TILE) * 64 * 2048;                  \
    const __bf16* hv_ = HvT + hvb + (TILE) * 64;                                \
    _Pragma("unroll")                                                           \
    for (int u = 0; u < 4; u++)                                                 \
      gload16(rc_ + rs_src[u], &Rs[BUF][(wv * 4 + u) * 512]);                   \
    _Pragma("unroll")                                                           \
    for (int u = 0; u < 2; u++)                                                 \
      gload16(hv_ + hs_src[u], &Hs[BUF][(wv * 2 + u) * 512]);                   \
  }

  f32x4 oacc[2][4] = {};   // [i][jd]; col=q(l16), row=d(quad*4+r)
  float rssq[2] = {};
  const int nt = S >> 6;

  STAGE(0, 0);
  __syncthreads();

  const int srcA = ((quad & 1) << 1) | (quad >> 1);
  const int adA = ((srcA << 4) | l16) << 2;
  const int adB = (((srcA ^ 1) << 4) | l16) << 2;
  const bool par = (quad & 1) != 0;
  const bool hi = (quad >> 1) != 0;
  const int key = l16 & 7;

  for (int it = 0; it < nt; ++it) {
    const int cur = it & 1;
    if (it + 1 < nt) STAGE(cur ^ 1, it + 1);   // in flight across full compute

    // ---- QK^T (swapped): sacc[jt][i] rows = kv, cols = q
    f32x4 sacc[4][2] = {};
#pragma unroll
    for (int s = 0; s < 4; s++) {
      const int co = ((4 * s + quad) ^ key) * 8;
#pragma unroll
      for (int jt = 0; jt < 4; jt++) {
        const bf16x8 rf = *(const bf16x8*)&Rs[cur][(jt * 16 + l16) * 128 + co];
#pragma unroll
        for (int i = 0; i < 2; i++)
          sacc[jt][i] = __builtin_amdgcn_mfma_f32_16x16x32_bf16(rf, qf[i][s], sacc[jt][i], 0, 0, 0);
      }
    }

    // ---- rssq (exact f32) + pack S to bf16 pairs
    unsigned pk[4][2][2];
#pragma unroll
    for (int jt = 0; jt < 4; jt++)
#pragma unroll
      for (int i = 0; i < 2; i++) {
        rssq[i] += sacc[jt][i][0] * sacc[jt][i][0] + sacc[jt][i][1] * sacc[jt][i][1] +
                   sacc[jt][i][2] * sacc[jt][i][2] + sacc[jt][i][3] * sacc[jt][i][3];
        union { __bf16 h2[2]; unsigned u; } p0, p1;
        p0.h2[0] = f2b(sacc[jt][i][0]); p0.h2[1] = f2b(sacc[jt][i][1]);
        p1.h2[0] = f2b(sacc[jt][i][2]); p1.h2[1] = f2b(sacc[jt][i][3]);
        pk[jt][i][0] = p0.u; pk[jt][i][1] = p1.u;
      }

    // ---- PV: O^T += HvT-frag (rows=d) x S^T-frag (cols=q, in-register bpermute)
#pragma unroll
    for (int s2 = 0; s2 < 2; s2++) {
      bf16x8 hf[4];
      const int co2 = ((4 * s2 + quad) ^ key) * 8;
#pragma unroll
      for (int jd = 0; jd < 4; jd++)
        hf[jd] = *(const bf16x8*)&Hs[cur][(jd * 16 + l16) * 64 + co2];
      const int jA = 2 * s2, jB = 2 * s2 + 1;
#pragma unroll
      for (int i = 0; i < 2; i++) {
        const unsigned o0 = par ? pk[jB][i][0] : pk[jA][i][0];
        const unsigned o1 = par ? pk[jB][i][1] : pk[jA][i][1];
        const unsigned o2 = par ? pk[jA][i][0] : pk[jB][i][0];
        const unsigned o3 = par ? pk[jA][i][1] : pk[jB][i][1];
        const unsigned r0 = (unsigned)__builtin_amdgcn_ds_bpermute(adA, (int)o0);
        const unsigned r1 = (unsigned)__builtin_amdgcn_ds_bpermute(adA, (int)o1);
        const unsigned r2 = (unsigned)__builtin_amdgcn_ds_bpermute(adB, (int)o2);
        const unsigned r3 = (unsigned)__builtin_amdgcn_ds_bpermute(adB, (int)o3);
        union { unsigned u[4]; bf16x8 v; } bw;
        bw.u[0] = hi ? r2 : r0;
        bw.u[1] = hi ? r3 : r1;
        bw.u[2] = hi ? r0 : r2;
        bw.u[3] = hi ? r1 : r3;
#pragma unroll
        for (int jd = 0; jd < 4; jd++)
          oacc[i][jd] = __builtin_amdgcn_mfma_f32_16x16x32_bf16(hf[jd], bw.v, oacc[i][jd], 0, 0, 0);
      }
    }
    __syncthreads();
  }
#undef STAGE

  // ---- normalize + packed store
#pragma unroll
  for (int i = 0; i < 2; i++) {
    float t = rssq[i];
    t += __shfl_xor(t, 16);
    t += __shfl_xor(t, 32);
    const float inv = 1.0f / fmaxf(sqrtf(t), 1e-12f);
    const size_t orow = (size_t)(b * S + q0 + wv * 32 + i * 16 + l16) * 1024 + h * 64;
#pragma unroll
    for (int jd = 0; jd < 4; jd++) {
      union { __bf16 h4[4]; uint2 u2; } o;
#pragma unroll
      for (int r = 0; r < 4; r++) o.h4[r] = f2b(oacc[i][jd][r] * inv);
      *(uint2*)&Aout[orow + jd * 16 + quad * 4] = o.u2;
    }
  }
}

// ---------------------------------------------------------------- launch
extern "C" void kernel_launch(void* const* d_in, const int* in_sizes, int n_in,
                              void* d_out, int out_size, void* d_ws, size_t ws_size,
                              hipStream_t stream) {
  const void* query = d_in[0];
  const void* Wz = d_in[3];
  const void* bz = d_in[4];
  const void* ln_g = d_in[5];
  const void* ln_b = d_in[6];
  const void* Wq = d_in[7];
  const void* bq = d_in[8];
  const void* Wr = d_in[9];
  const void* br = d_in[10];
  const void* Wh = d_in[11];
  const void* bh = d_in[12];
  const void* Wphi = d_in[13];
  const void* bphi = d_in[14];
  const void* Wo = d_in[15];
  const void* bo = d_in[16];

  const int n_q = in_sizes[0];   // B*S*1024
  const int Srows = n_q >> 10;   // B*S
  const int S = Srows >> 1;      // B = 2

  char* ws = (char*)d_ws;
  const size_t MB = 1024 * 1024;

  int* mode = (int*)(ws);
  __bf16* sv = (__bf16*)(ws + 4096);
  __bf16* bz_c   = sv + 0 * 4096;
  __bf16* lng_c  = sv + 1 * 4096;
  __bf16* lnb_c  = sv + 2 * 4096;
  __bf16* bo_c   = sv + 3 * 4096;
  __bf16* bphi_c = sv + 4 * 4096;
  __bf16* wphi_c = sv + 5 * 4096;   // 4096 elems
  __bf16* bqrh   = sv + 6 * 4096;   // 3072 elems
  __bf16* WzT    = (__bf16*)(ws + 1 * MB);   // 2 MB
  __bf16* WoT    = (__bf16*)(ws + 3 * MB);   // 2 MB
  __bf16* WqrhT  = (__bf16*)(ws + 5 * MB);   // 6 MB
  float*  Zraw   = (float*) (ws + 11 * MB);  // 16 MB, dead after ln
  __bf16* Z      = (__bf16*)(ws + 27 * MB);  // 8 MB, dead after qrh gemm
  __bf16* Qf     = (__bf16*)(ws + 35 * MB);  // 8 MB, dead after phasor Q
  __bf16* Rf     = (__bf16*)(ws + 43 * MB);  // 8 MB, dead after phasor R
  __bf16* Hv     = (__bf16*)(ws + 51 * MB);  // 8 MB, dead after hvt
  __bf16* Qbf    = (__bf16*)(ws + 59 * MB);  // 8 MB, dead after z-gemm
  __bf16* Rc     = (__bf16*)(ws + 59 * MB);  // 16 MB (top = 75 MB, proven safe)
  __bf16* Qc     = (__bf16*)(ws + 11 * MB);  // 16 MB over dead Zraw
  __bf16* HvT    = (__bf16*)(ws + 27 * MB);  // 8 MB over dead Z
  __bf16* Aout   = (__bf16*)(ws + 35 * MB);  // 8 MB over dead Qf

  dim3 blk(256);
  detect_k<<<1, 64, 0, stream>>>((const unsigned short*)query, mode);

  CvtJobs cj;
  cj.src[0] = bz;   cj.dst[0] = bz_c;
  cj.src[1] = ln_g; cj.dst[1] = lng_c;
  cj.src[2] = ln_b; cj.dst[2] = lnb_c;
  cj.src[3] = bo;   cj.dst[3] = bo_c;
  cj.src[4] = bphi; cj.dst[4] = bphi_c;
  cj.src[5] = Wphi; cj.dst[5] = wphi_c;
  cj.src[6] = bq;   cj.dst[6] = bqrh;
  cj.src[7] = br;   cj.dst[7] = bqrh + 1024;
  cj.src[8] = bh;   cj.dst[8] = bqrh + 2048;
  cvt_all_k<<<12, blk, 0, stream>>>(cj, mode);

  TJobs tj;
  tj.src[0] = Wz; tj.dst[0] = WzT;
  tj.src[1] = Wo; tj.dst[1] = WoT;
  tj.src[2] = Wq; tj.dst[2] = WqrhT;
  tj.src[3] = Wr; tj.dst[3] = WqrhT + 1024 * 1024;
  tj.src[4] = Wh; tj.dst[4] = WqrhT + 2 * 1024 * 1024;
  tcvt_all_k<<<dim3(16, 16, 5), blk, 0, stream>>>(tj, mode);

  qcvt_k<<<(Srows * 1024 / 8 + 255) / 256, blk, 0, stream>>>(query, Qbf, Srows * 128, mode);

  const int mcnt = Srows / 64;
  gemm2p_k<true><<<16 * mcnt, blk, 0, stream>>>(Qbf, WzT, bz_c, (void*)Zraw,
                                                Srows, 1024, 1024);
  ln_k<<<Srows, blk, 0, stream>>>(Zraw, lng_c, lnb_c, Z);
  qrh2p_k<<<24 * mcnt, blk, 0, stream>>>(Z, WqrhT, bqrh, Qf, Rf, Hv, Srows);
  phasor_mfma_k<<<dim3((Srows * 16) / 128, 2), blk, 0, stream>>>(Qf, Rf, wphi_c, bphi_c, Qc, Rc);
  hvt_k<<<dim3(S / 64, 16, 2), blk, 0, stream>>>(Hv, HvT, S);
  attn_k<<<dim3((S / 128) * 32), blk, 0, stream>>>(Qc, Rc, HvT, Aout, S);
  gemm2p_k<true><<<16 * mcnt, blk, 0, stream>>>(Aout, WoT, bo_c, d_out,
                                                Srows, 1024, 1024);
}